// Round 11
// baseline (303.799 us; speedup 1.0000x reference)
//
#include <hip/hip_runtime.h>
#include <stdint.h>

// SNN forward: prep -> conv1+scan(fused) -> pool1+pad(fused) -> conv2+scan
// (MFMA) -> pool2+pad(fused) -> conv3+scan(MFMA) -> sT -> fc(MFMA) -> reduce
// -> scan.
// Neuron: u=.75u+x; v=.96875v+u; s=(v>=100); v*=(1-s). Spikes u8 in d_ws.
// R9:  FC GEMM on matrix cores (exact 3-way bf16 weight split).
// R11: conv2/conv3 on matrix cores via pre-padded/delayed sP + A-frag weights.
// R12: scan fused INTO the MFMA convs; XCD-contiguous block swizzle.
// R13: conv1+scan fused; fc_gemm 4-wave blocks.
// R14: fc/conv1 XCD swizzles; pool+pad fused (pool_pad).
// R15: fc_gemm 8 waves/512 thr; prep consolidation.
// R17: conv_scan_mfma PB halved -> 4 blocks/CU (confirmed 244us).
// R18: conv1_scan LDS tap staging -- REGRESSION (+6us): kernel was never
// load-bound (warm HBM 26MB @ 8%), it is scan-utilization-bound (64/256
// threads in the serial phase; VALUBusy 35% = stall-dominated).
// R19: conv1_scan rebuilt: block=(n,hy), 320 thr = 320 rows (8o x 40wx),
// t-chunked x4. Per chunk: direct R9-style taps (18 float4, same q order ->
// bitwise-same x) -> LDS [320][35] (odd stride, 2-way-free) -> ALL 320
// threads scan their row chunk (u,v persist in regs) -> direct spike write.
// Scan util 64/256 -> 320/320; LDS 44.8KB -> 3 blocks/CU; grid 640 fully
// resident. Single-variable round; rest identical to R17.

#define T 128
#define AI 0.75f
#define AV 0.96875f
#define THETA 100.0f

typedef __attribute__((ext_vector_type(8))) short v8s;    // 8 x bf16 bits
typedef __attribute__((ext_vector_type(16))) float v16f;  // 32x32 acc

__device__ __forceinline__ void neuron_step(float x, float& u, float& v, float& s) {
    u = AI * u + x;
    v = AV * v + u;
    s = (v >= THETA) ? 1.0f : 0.0f;
    v = v * (1.0f - s);
}

// ---------------- conv1 + scan fused: spikes fp32 -> s1 u8 ------------------
// Block = (n, hy): 320 thr = 40 wx x 8 tt (compute) = 320 rows (scan).
// 4 t-chunks of 32: {taps -> x -> LDS} barrier {all-thread row scan} barrier.
__global__ __launch_bounds__(320, 3) void conv1_scan(
    const float* __restrict__ in, const float* __restrict__ cw,
    uint8_t* __restrict__ sout)
{
    __shared__ float ldsX[320 * 35];             // 44,800 B
    int bid0 = blockIdx.x;                       // 640 = 16n x 40hy
    int bid = (bid0 & 7) * 80 + (bid0 >> 3);     // XCD-contiguous
    int hy = bid % 40;
    int n  = bid / 40;
    int tid = threadIdx.x;
    int wx = tid >> 3, tt = tid & 7;             // compute mapping
    int so = tid / 40, swx = tid % 40;           // scan-row mapping

    bool okh[3] = {hy > 0, true, hy < 39};
    bool okw[3] = {wx > 0, true, wx < 39};

    float u = 0.f, v = 0.f;                      // scan state, persists chunks
    uint32_t* op = (uint32_t*)(sout +
        (((size_t)(n * 8 + so) * 40 + hy) * 40 + swx) * T);

    #pragma unroll 1
    for (int ch = 0; ch < 4; ch++) {
        int t0 = ch * 32 + tt * 4;
        // ---- compute phase: direct taps (same q order/values as R9) ----
        float4 tap[18];
        #pragma unroll
        for (int c = 0; c < 2; c++)
          #pragma unroll
          for (int dh = 0; dh < 3; dh++)
            #pragma unroll
            for (int dw = 0; dw < 3; dw++) {
                int q = c * 9 + dh * 3 + dw;
                int gy = hy + dh - 1, gx = wx + dw - 1;
                bool ok = okh[dh] && okw[dw];
                tap[q] = ok ? *(const float4*)(in +
                    (((size_t)(n * 2 + c) * 40 + gy) * 40 + gx) * T + t0)
                            : make_float4(0.f, 0.f, 0.f, 0.f);
            }
        __syncthreads();                         // prev scan reads complete
        #pragma unroll
        for (int o = 0; o < 8; o++) {
            const float* wp = cw + o * 18;       // uniform -> s_load
            float a0 = 0.f, a1 = 0.f, a2 = 0.f, a3 = 0.f;
            #pragma unroll
            for (int q = 0; q < 18; q++) {
                a0 += wp[q] * tap[q].x;  a1 += wp[q] * tap[q].y;
                a2 += wp[q] * tap[q].z;  a3 += wp[q] * tap[q].w;
            }
            float* xr = &ldsX[(o * 40 + wx) * 35 + tt * 4];
            xr[0] = a0 * 20.0f; xr[1] = a1 * 20.0f;
            xr[2] = a2 * 20.0f; xr[3] = a3 * 20.0f;
        }
        __syncthreads();                         // x ready
        // ---- scan phase: all 320 threads, one row each ----
        const float* xr = &ldsX[tid * 35];
        uint32_t ob[8];
        #pragma unroll
        for (int tb = 0; tb < 8; tb++) {
            float s0, s1, s2, s3;
            neuron_step(xr[tb * 4 + 0], u, v, s0);
            neuron_step(xr[tb * 4 + 1], u, v, s1);
            neuron_step(xr[tb * 4 + 2], u, v, s2);
            neuron_step(xr[tb * 4 + 3], u, v, s3);
            ob[tb] = (uint32_t)s0 | ((uint32_t)s1 << 8) |
                     ((uint32_t)s2 << 16) | ((uint32_t)s3 << 24);
        }
        *(uint4*)&op[ch * 8]     = make_uint4(ob[0], ob[1], ob[2], ob[3]);
        *(uint4*)&op[ch * 8 + 4] = make_uint4(ob[4], ob[5], ob[6], ob[7]);
    }
}

// ---------------- pool_pad: 2x2 sum + scan + delay -> sP bf16 directly ------
template<int C, int HO, int WO>
__global__ __launch_bounds__(320) void pool_pad(
    const uint8_t* __restrict__ in, const float* __restrict__ pw_ptr,
    uint16_t* __restrict__ sP)
{
    constexpr int CB = 320 / C;                  // cells per block (40 or 20)
    constexpr int GP = (HO * WO) / CB;           // cell-groups per n (10 or 5)
    __shared__ uint8_t raw[320 * 132];           // 42,240 B, two overlaid uses
    uint32_t* ldsF = (uint32_t*)raw;             // [320 rows][20 u32] staging
    uint8_t*  sbuf = raw;                        // [320 rows][132 B] spikes

    int bid = blockIdx.x;                        // 16n x GP
    int grp = bid % GP, n = bid / GP;
    int tid = threadIdx.x;
    float pw = pw_ptr[0];

    float u = 0.f, v = 0.f;
    uint32_t ob[32];
    uint32_t carry = 0;

    #pragma unroll
    for (int tb = 0; tb < 2; tb++) {
        __syncthreads();
        #pragma unroll
        for (int k = 0; k < 4; k++) {
            int f = tid + k * 320;
            int row = f >> 2, q = f & 3;
            int c = row / CB, p = row % CB;
            int hw = grp * CB + p;
            int wx = hw % WO, hy = hw / WO;
            const uint8_t* p00 = in +
                (((size_t)(n * C + c) * (2 * HO) + 2 * hy) * (2 * WO) + 2 * wx) * T;
            int off = tb * 64 + q * 16;
            uint4 a = *(const uint4*)(p00 + off);
            uint4 b = *(const uint4*)(p00 + T + off);
            uint4 cc = *(const uint4*)(p00 + 2 * WO * T + off);
            uint4 d = *(const uint4*)(p00 + 2 * WO * T + T + off);
            *(uint4*)&ldsF[row * 20 + q * 4] =
                make_uint4(a.x + b.x + cc.x + d.x, a.y + b.y + cc.y + d.y,
                           a.z + b.z + cc.z + d.z, a.w + b.w + cc.w + d.w);
        }
        __syncthreads();
        #pragma unroll
        for (int q = 0; q < 4; q++) {
            uint4 w = *(const uint4*)&ldsF[tid * 20 + q * 4];
            uint32_t words[4] = {w.x, w.y, w.z, w.w};
            #pragma unroll
            for (int j = 0; j < 4; j++) {
                uint32_t cur = words[j];
                uint32_t del = (cur << 8) | carry;   // delay_shift bytes
                carry = cur >> 24;
                float s0, s1, s2, s3;
                neuron_step(pw * (float)(del & 0xffu),         u, v, s0);
                neuron_step(pw * (float)((del >> 8) & 0xffu),  u, v, s1);
                neuron_step(pw * (float)((del >> 16) & 0xffu), u, v, s2);
                neuron_step(pw * (float)((del >> 24) & 0xffu), u, v, s3);
                ob[tb * 16 + q * 4 + j] = (uint32_t)s0 | ((uint32_t)s1 << 8) |
                                          ((uint32_t)s2 << 16) | ((uint32_t)s3 << 24);
            }
        }
    }

    // phase 3: spikes -> LDS byte rows (staging reads complete at barrier)
    __syncthreads();
    #pragma unroll
    for (int j = 0; j < 32; j++)
        *(uint32_t*)&sbuf[tid * 132 + j * 4] = ob[j];
    __syncthreads();

    // phase 4: transpose-write sP[cell][tau][16c], conv delay via tau-1
    constexpr int CHK = CB * 128;                // 32B chunks (5120 or 2560)
    #pragma unroll
    for (int k = 0; k < CHK / 320; k++) {
        int ci = k * 320 + tid;
        int p = ci >> 7, tau = ci & 127;
        int hw = grp * CB + p;
        int wx = hw % WO, hy = hw / WO;
        uint32_t wb[8];
        #pragma unroll
        for (int e = 0; e < 16; e += 2) {
            uint32_t lo = 0u, hi = 0u;
            if (tau >= 1) {
                if (e < C)     lo = sbuf[(e * CB + p) * 132 + tau - 1] ? 0x3F80u : 0u;
                if (e + 1 < C) hi = sbuf[((e + 1) * CB + p) * 132 + tau - 1] ? 0x3F80u : 0u;
            }
            wb[e >> 1] = lo | (hi << 16);
        }
        uint16_t* dst = sP + ((size_t)((n * (HO + 2) + hy + 1) * (WO + 2)
                                       + wx + 1)) * 2048 + tau * 16;
        *(uint4*)dst       = make_uint4(wb[0], wb[1], wb[2], wb[3]);
        *(uint4*)(dst + 8) = make_uint4(wb[4], wb[5], wb[6], wb[7]);
    }
}

// ---------------- prep: wsplit + apack_w + halo zeroing, one dispatch -------
__global__ __launch_bounds__(256) void prep(
    const float* __restrict__ fw, const float* __restrict__ c2w,
    const float* __restrict__ c3w, uint16_t* __restrict__ bs,
    uint16_t* __restrict__ apk, uint16_t* __restrict__ s2P,
    uint16_t* __restrict__ s4P)
{
    int bid = blockIdx.x;
    int tid = threadIdx.x;
    if (bid < 1600) {
        int i = bid * 256 + tid;                 // 409,600 threads, 4 elems
        float4 wv = *(const float4*)(fw + i * 4);
        float w4[4] = {wv.x, wv.y, wv.z, wv.w};
        uint16_t h[4], m[4], l[4];
        #pragma unroll
        for (int j = 0; j < 4; j++) {
            uint32_t b0 = __float_as_uint(w4[j]);
            h[j] = (uint16_t)(b0 >> 16);
            float r1 = w4[j] - __uint_as_float(b0 & 0xFFFF0000u);   // exact
            uint32_t b1 = __float_as_uint(r1);
            m[j] = (uint16_t)(b1 >> 16);
            float r2 = r1 - __uint_as_float(b1 & 0xFFFF0000u);      // exact
            l[j] = (uint16_t)(__float_as_uint(r2) >> 16);           // exact
        }
        *(ushort4*)(bs +       0 + i * 4) = make_ushort4(h[0], h[1], h[2], h[3]);
        *(ushort4*)(bs + 1638400 + i * 4) = make_ushort4(m[0], m[1], m[2], m[3]);
        *(ushort4*)(bs + 3276800 + i * 4) = make_ushort4(l[0], l[1], l[2], l[3]);
    } else if (bid < 1614) {
        int unit = (bid - 1600) * 4 + (tid >> 6);    // 0..55, 54 used
        if (unit >= 54) return;
        int conv = unit / 27;
        int plane = (unit % 27) / 9;
        int dlt = unit % 9;
        int lane = tid & 63;
        int o = lane & 31, chi = (lane >> 5) * 8;
        int CO = conv ? 32 : 16;
        int CI = conv ? 16 : 8;
        const float* Wp = conv ? c3w : c2w;
        uint32_t wb[4] = {0u, 0u, 0u, 0u};
        #pragma unroll
        for (int e = 0; e < 8; e++) {
            int c = chi + e;
            float w = (o < CO && c < CI) ? Wp[((size_t)o * CI + c) * 9 + dlt] : 0.f;
            uint32_t b0 = __float_as_uint(w);
            uint16_t hi = (uint16_t)(b0 >> 16);
            float r1 = w - __uint_as_float(b0 & 0xFFFF0000u);     // exact
            uint32_t b1 = __float_as_uint(r1);
            uint16_t md = (uint16_t)(b1 >> 16);
            float r2 = r1 - __uint_as_float(b1 & 0xFFFF0000u);    // exact
            uint16_t lo = (uint16_t)(__float_as_uint(r2) >> 16);  // exact
            uint32_t pv = (plane == 0) ? hi : ((plane == 1) ? md : lo);
            wb[e >> 1] |= pv << ((e & 1) * 16);
        }
        *(uint4*)(apk + ((size_t)conv * 27 + plane * 9 + dlt) * 512 + lane * 8) =
            make_uint4(wb[0], wb[1], wb[2], wb[3]);
    } else {
        int hid = bid - 1614;
        uint8_t* dst;
        if (hid < 1344) {                        // conv2 ring: 16n x 84
            int n = hid / 84, r = hid % 84;
            int hy, wx;
            if (r < 22)      { hy = 0;  wx = r; }
            else if (r < 44) { hy = 21; wx = r - 22; }
            else { int r2 = r - 44; hy = 1 + (r2 >> 1); wx = (r2 & 1) ? 21 : 0; }
            dst = (uint8_t*)s2P + ((size_t)(n * 484) + hy * 22 + wx) * 4096;
        } else {                                 // conv3 ring: 16n x 44
            int h2 = hid - 1344;
            int n = h2 / 44, r = h2 % 44;
            int hy, wx;
            if (r < 12)      { hy = 0;  wx = r; }
            else if (r < 24) { hy = 11; wx = r - 12; }
            else { int r2 = r - 24; hy = 1 + (r2 >> 1); wx = (r2 & 1) ? 11 : 0; }
            dst = (uint8_t*)s4P + ((size_t)(n * 144) + hy * 12 + wx) * 4096;
        }
        *(uint4*)(dst + tid * 16) = make_uint4(0u, 0u, 0u, 0u);
    }
}

// ---------------- conv_scan_mfma: MFMA conv + in-block LIF scan -------------
// Block = 256 thr (4 waves = 4 tau-chunks) x PB positions, all COUT, all T.
// R17: PB halved -> LDS 33,280 B -> 4 blocks/CU, 4 waves/SIMD.
template<int COUT, int PB, int H, int W>
__global__ __launch_bounds__(256, 2) void conv_scan_mfma(
    const uint16_t* __restrict__ sP, const uint16_t* __restrict__ apk,
    float scale, uint8_t* __restrict__ sout)
{
    constexpr int ROWS = COUT * PB;              // 64
    __shared__ float ldsF[ROWS * 130];           // 33,280 B
    constexpr int HW = H * W;
    constexpr int GP = HW / PB;
    int per = (16 * GP) >> 3;                    // blocks per XCD
    int vbid = (blockIdx.x & 7) * per + (blockIdx.x >> 3);
    int n = vbid / GP, grp = vbid % GP;
    int tid = threadIdx.x;
    int wv = tid >> 6, lane = tid & 63;
    int l31 = lane & 31, lhi = lane >> 5;
    int t0 = wv * 32;

    const uint16_t* ap = apk + (size_t)lane * 8;
    v8s a0[9], a1[9], a2[9];
    #pragma unroll
    for (int d = 0; d < 9; d++) {
        a0[d] = *(const v8s*)(ap + d * 512);
        a1[d] = *(const v8s*)(ap + (9 + d) * 512);
        a2[d] = *(const v8s*)(ap + (18 + d) * 512);
    }

    #pragma unroll
    for (int p = 0; p < PB; p++) {
        int hw = grp * PB + p;
        int hy = hw / W, wx = hw % W;
        v8s bfr[9];
        #pragma unroll
        for (int d = 0; d < 9; d++) {
            int dh = d / 3, dw = d % 3;
            const uint16_t* src = sP
                + ((size_t)((n * (H + 2) + hy + dh) * (W + 2) + wx + dw)) * 2048
                + (t0 + l31) * 16 + lhi * 8;
            bfr[d] = *(const v8s*)src;
        }
        v16f ac0, ac1, ac2;
        #pragma unroll
        for (int e = 0; e < 16; e++) { ac0[e] = 0.f; ac1[e] = 0.f; ac2[e] = 0.f; }
        #pragma unroll
        for (int d = 0; d < 9; d++) {
            ac0 = __builtin_amdgcn_mfma_f32_32x32x16_bf16(a0[d], bfr[d], ac0, 0, 0, 0);
            ac1 = __builtin_amdgcn_mfma_f32_32x32x16_bf16(a1[d], bfr[d], ac1, 0, 0, 0);
            ac2 = __builtin_amdgcn_mfma_f32_32x32x16_bf16(a2[d], bfr[d], ac2, 0, 0, 0);
        }
        constexpr int NR = (COUT == 32) ? 16 : 8;
        #pragma unroll
        for (int r = 0; r < NR; r++) {
            int o = (r & 3) + 8 * (r >> 2) + 4 * lhi;
            ldsF[(o * PB + p) * 130 + t0 + l31] =
                (ac0[r] + ac1[r] + ac2[r]) * scale;
        }
    }
    __syncthreads();
    if (tid < ROWS) {
        int o = tid / PB, p = tid % PB;
        int hw = grp * PB + p;
        float u = 0.f, v = 0.f;
        uint32_t ob[32];
        const float* xr = &ldsF[tid * 130];
        #pragma unroll
        for (int tb = 0; tb < 32; tb++) {
            float2 xa = *(const float2*)(xr + tb * 4);
            float2 xb = *(const float2*)(xr + tb * 4 + 2);
            float s0, s1, s2, s3;
            neuron_step(xa.x, u, v, s0); neuron_step(xa.y, u, v, s1);
            neuron_step(xb.x, u, v, s2); neuron_step(xb.y, u, v, s3);
            ob[tb] = (uint32_t)s0 | ((uint32_t)s1 << 8) |
                     ((uint32_t)s2 << 16) | ((uint32_t)s3 << 24);
        }
        uint32_t* op = (uint32_t*)(sout + ((size_t)(n * COUT + o) * HW + hw) * 128);
        #pragma unroll
        for (int k = 0; k < 8; k++)
            *(uint4*)&op[k * 4] =
                make_uint4(ob[k*4], ob[k*4+1], ob[k*4+2], ob[k*4+3]);
    }
}

// ---------------- sT: s5 u8 [16][3200][128] -> At bf16 [16][128][3200] ------
__global__ __launch_bounds__(256) void sT_bf16(
    const uint8_t* __restrict__ s5, uint16_t* __restrict__ At)
{
    __shared__ uint8_t tile[64 * 132];           // 64 c-rows x 128 t (+4 pad)
    int bid = blockIdx.x;                        // 800 = 16 n x 50 chunks
    int n = bid / 50;
    int c0 = (bid % 50) * 64;
    int tid = threadIdx.x;
    {
        int row = tid >> 2, q = tid & 3;
        const uint8_t* src = s5 + ((size_t)(n * 3200 + c0 + row)) * T + q * 32;
        *(uint4*)&tile[row * 132 + q * 32]      = *(const uint4*)src;
        *(uint4*)&tile[row * 132 + q * 32 + 16] = *(const uint4*)(src + 16);
    }
    __syncthreads();
    int t = tid >> 1, half = tid & 1;
    uint32_t wb[16];
    if (t == 0) {
        #pragma unroll
        for (int j = 0; j < 16; j++) wb[j] = 0u;
    } else {
        #pragma unroll
        for (int j = 0; j < 16; j++) {
            uint32_t lo = tile[(half * 32 + 2 * j) * 132 + (t - 1)] ? 0x3F80u : 0u;
            uint32_t hi = tile[(half * 32 + 2 * j + 1) * 132 + (t - 1)] ? 0x3F80u : 0u;
            wb[j] = lo | (hi << 16);
        }
    }
    uint16_t* dst = At + ((size_t)(n * 128 + t)) * 3200 + c0 + half * 32;
    #pragma unroll
    for (int k = 0; k < 4; k++)
        *(uint4*)(dst + k * 8) = make_uint4(wb[k*4], wb[k*4+1], wb[k*4+2], wb[k*4+3]);
}

// ---------------- FC GEMM on matrix cores (8 waves, 2x4 split) --------------
#define GLDS16(g, s) __builtin_amdgcn_global_load_lds( \
    (const __attribute__((address_space(1))) uint32_t*)(g), \
    (__attribute__((address_space(3))) uint32_t*)(s), 16, 0, 0)

__global__ __launch_bounds__(512, 4) void fc_gemm_mfma(
    const uint16_t* __restrict__ At,   // [16][128][3200] bf16
    const uint16_t* __restrict__ Bs,   // [3][512][3200] bf16
    float* __restrict__ ypart)         // [10][16][128][512] f32
{
    __shared__ uint8_t lds[65536];     // A [128][64]bf16 @0; B 3x[128][64] @16K
    int bid0 = blockIdx.x;             // 640 = 10ks x 4ob x 16n (n fastest)
    int bid = (bid0 & 7) * 80 + (bid0 >> 3);     // XCD-contiguous
    int n  = bid & 15;
    int ob = (bid >> 4) & 3;
    int ks = bid >> 6;
    int o0 = ob * 128;
    int cbase = ks * 320;

    int tid = threadIdx.x;
    int w8 = tid >> 6;                 // wave 0..7
    int wm = w8 >> 2;                  // t-half
    int wn = w8 & 3;                   // o-quarter
    int lane = tid & 63;
    int l31 = lane & 31;
    int lhi = lane >> 5;               // k-half within frag
    int rb = lane >> 3;                // staging: row-in-8
    int gsw = (lane & 7) ^ (rb & 7);   // pre-swizzled source granule

    v16f acc[2];
    #pragma unroll
    for (int mi = 0; mi < 2; mi++)
        #pragma unroll
        for (int e = 0; e < 16; e++) acc[mi][e] = 0.0f;

    const uint16_t* Abase = At + (size_t)(n * 128) * 3200 + gsw * 8;

    for (int kc = 0; kc < 5; kc++) {
        int c0 = cbase + kc * 64;
        // ---- stage A: 16 x 1KB chunks, chunk cid = i*8 + w8 ----
        #pragma unroll
        for (int i = 0; i < 2; i++) {
            int cid = i * 8 + w8;
            const uint16_t* src = Abase + (size_t)(cid * 8 + rb) * 3200 + c0;
            GLDS16(src, lds + cid * 1024);
        }
        // ---- stage B: 48 x 1KB chunks ----
        #pragma unroll
        for (int j = 0; j < 6; j++) {
            int cid = j * 8 + w8;
            int f0 = cid * 1024;
            int s = f0 >> 14;                    // split plane
            int r = ((f0 & 16383) >> 7) + rb;    // o-local row
            const uint16_t* src = Bs + (size_t)(s * 512 + o0 + r) * 3200
                                     + c0 + gsw * 8;
            GLDS16(src, lds + 16384 + f0);
        }
        __syncthreads();                         // drains vmcnt before barrier
        // ---- compute: 4 kf x (3 splits x 2 mi) MFMA per wave ----
        #pragma unroll
        for (int kf = 0; kf < 4; kf++) {
            int gc = kf * 2 + lhi;
            v8s av[2];
            #pragma unroll
            for (int mi = 0; mi < 2; mi++) {
                int t = wm * 64 + mi * 32 + l31;
                av[mi] = *(const v8s*)(lds + t * 128 + ((gc ^ (t & 7)) << 4));
            }
            #pragma unroll
            for (int s = 0; s < 3; s++) {
                int r = wn * 32 + l31;
                v8s bv = *(const v8s*)(lds + 16384 + s * 16384 + r * 128
                                       + ((gc ^ (r & 7)) << 4));
                #pragma unroll
                for (int mi = 0; mi < 2; mi++)
                    acc[mi] = __builtin_amdgcn_mfma_f32_32x32x16_bf16(
                        av[mi], bv, acc[mi], 0, 0, 0);
            }
        }
        __syncthreads();                         // LDS safe before next stage
    }
    // ---- epilogue: C/D layout col=lane&31, row=(r&3)+8*(r>>2)+4*(lane>>5) --
    float* yp = ypart + (size_t)ks * 1048576 + (size_t)n * 65536;
    int o = o0 + wn * 32 + l31;
    #pragma unroll
    for (int mi = 0; mi < 2; mi++) {
        #pragma unroll
        for (int r = 0; r < 16; r++) {
            int trow = wm * 64 + mi * 32 + (r & 3) + 8 * (r >> 2) + 4 * lhi;
            yp[trow * 512 + o] = acc[mi][r];
        }
    }
}

// ---------------- FC partial reduce (10 partials, float4) -------------------
__global__ __launch_bounds__(256) void fc_reduce(
    const float4* __restrict__ yp, float4* __restrict__ ys)
{
    int id = blockIdx.x * 256 + threadIdx.x;          // 262,144
    float4 x = yp[id];
    #pragma unroll
    for (int k = 1; k < 10; k++) {
        float4 y = yp[(size_t)k * 262144 + id];
        x.x += y.x; x.y += y.y; x.z += y.z; x.w += y.w;
    }
    ys[id] = x;
}

__global__ __launch_bounds__(64) void fc_scan(
    const float* __restrict__ ysum,   // [16][128][512]
    float* __restrict__ out)          // [16][512][128]
{
    int id = blockIdx.x * 64 + threadIdx.x;           // 8192
    int o = id & 511;
    int n = id >> 9;
    float u = 0.f, v = 0.f;
    float prev = 0.f;                 // final delay_shift
    for (int tb = 0; tb < T / 4; tb++) {
        float b0, b1, b2, b3;
        float x, s;
        x = ysum[(n * T + tb * 4 + 0) * 512 + o]; neuron_step(x, u, v, s); b0 = prev; prev = s;
        x = ysum[(n * T + tb * 4 + 1) * 512 + o]; neuron_step(x, u, v, s); b1 = prev; prev = s;
        x = ysum[(n * T + tb * 4 + 2) * 512 + o]; neuron_step(x, u, v, s); b2 = prev; prev = s;
        x = ysum[(n * T + tb * 4 + 3) * 512 + o]; neuron_step(x, u, v, s); b3 = prev; prev = s;
        *(float4*)&out[((size_t)(n * 512 + o)) * T + tb * 4] = make_float4(b0, b1, b2, b3);
    }
}

// ---------------- launch ----------------------------------------------------
extern "C" void kernel_launch(void* const* d_in, const int* in_sizes, int n_in,
                              void* d_out, int out_size, void* d_ws, size_t ws_size,
                              hipStream_t stream) {
    const float* spike = (const float*)d_in[0];   // [16][2][40][40][128]
    const float* c1w   = (const float*)d_in[1];   // [8][2][3][3]
    const float* c2w   = (const float*)d_in[2];   // [16][8][3][3]
    const float* c3w   = (const float*)d_in[3];   // [32][16][3][3]
    const float* p1w   = (const float*)d_in[4];   // scalar
    const float* p2w   = (const float*)d_in[5];   // scalar
    const float* fcw   = (const float*)d_in[6];   // [512][3200]
    float* out = (float*)d_out;                   // [16][512][128]

    char* ws = (char*)d_ws;
    // Lifetime-ordered map (max 156,162,048):
    uint8_t*  s1    = (uint8_t*)(ws);             // -> 26,214,400
    uint16_t* Bs16  = (uint16_t*)(ws + 26214400); // -> 36,044,800 (alive->fc)
    uint16_t* Apk   = (uint16_t*)(ws + 36044800); // -> 36,100,096 (alive->conv3)
    uint16_t* s2P   = (uint16_t*)(ws + 36100096); // -> 67,819,520
    uint8_t*  s3    = (uint8_t*)(ws + 67819520);  // -> 80,926,720
    uint16_t* s4P   = (uint16_t*)(ws + 80926720); // -> 90,363,904
    uint8_t*  s5    = (uint8_t*)(ws + 90363904);  // -> 96,917,504
    uint16_t* At16  = (uint16_t*)(ws + 96917504); // -> 110,024,704
    float*    ypart = (float*)(ws + 110024704);   // -> 151,967,744
    float*    ysumb = (float*)(ws + 151967744);   // -> 156,162,048

    prep<<<3662, 256, 0, stream>>>(fcw, c2w, c3w, Bs16, Apk, s2P, s4P);
    conv1_scan<<<640, 320, 0, stream>>>(spike, c1w, s1);

    pool_pad<8, 20, 20><<<160, 320, 0, stream>>>(s1, p1w, s2P);
    conv_scan_mfma<16, 4, 20, 20><<<1600, 256, 0, stream>>>(s2P, Apk, 100.0f, s3);

    pool_pad<16, 10, 10><<<80, 320, 0, stream>>>(s3, p2w, s4P);
    conv_scan_mfma<32, 2, 10, 10><<<800, 256, 0, stream>>>(s4P, Apk + 13824, 100.0f, s5);

    sT_bf16<<<800, 256, 0, stream>>>(s5, At16);
    fc_gemm_mfma<<<640, 512, 0, stream>>>(At16, Bs16, ypart);
    fc_reduce<<<1024, 256, 0, stream>>>((const float4*)ypart, (float4*)ysumb);
    fc_scan<<<128, 64, 0, stream>>>(ysumb, out);
}

// Round 12
// 245.412 us; speedup vs baseline: 1.2379x; 1.2379x over previous
//
#include <hip/hip_runtime.h>
#include <stdint.h>

// SNN forward: prep -> conv1+scan(fused) -> pool1+pad(fused) -> conv2+scan
// (MFMA) -> pool2+pad(fused) -> conv3+scan(MFMA) -> sT -> fc(MFMA) ->
// fc_scan(fused 10-way reduce + LIF + delay).
// Neuron: u=.75u+x; v=.96875v+u; s=(v>=100); v*=(1-s). Spikes u8 in d_ws.
// R9:  FC GEMM on matrix cores (exact 3-way bf16 weight split).
// R11: conv2/conv3 on matrix cores via pre-padded/delayed sP + A-frag weights.
// R12: scan fused INTO the MFMA convs; XCD-contiguous block swizzle.
// R13: conv1+scan fused; R14: XCD swizzles + pool_pad; R15: fc 8-wave + prep.
// R17: conv_scan_mfma PB halved -> 4 blocks/CU (confirmed 244us, best).
// R18/R19: two conv1_scan restructures (LDS tap staging; 320-thr full-util
// scan) BOTH regressed (+6us / +38us): the kernel is not load-bound and the
// 64/256 scan phase was already TLP-covered at 4 blocks/CU; R19's 640-block
// grid (2.5/CU) + 8 barriers/block serialized it. REVERTED to R17 version.
// R20: fc_reduce folded into fc_scan (same k-ascending sum order ->
// bitwise-identical input to the neuron); deletes the 8.4MB ysum bounce
// and one dispatch. Only tail-of-pipeline change vs the 244us R9 state.

#define T 128
#define AI 0.75f
#define AV 0.96875f
#define THETA 100.0f

typedef __attribute__((ext_vector_type(8))) short v8s;    // 8 x bf16 bits
typedef __attribute__((ext_vector_type(16))) float v16f;  // 32x32 acc

__device__ __forceinline__ void neuron_step(float x, float& u, float& v, float& s) {
    u = AI * u + x;
    v = AV * v + u;
    s = (v >= THETA) ? 1.0f : 0.0f;
    v = v * (1.0f - s);
}

// ---------------- conv1 + scan fused: spikes fp32 -> s1 u8 (R17 version) ----
// Block = (n, hy, 8-wx group); 256 thr = 8 wx x 32 t-threads.
// Phase 1: x[o][wx][t] -> LDS (FMA order identical to old conv1_x).
// Phase 2: 64 threads scan one (o,wx) row each over t, write u8 spikes.
__global__ __launch_bounds__(256) void conv1_scan(
    const float* __restrict__ in, const float* __restrict__ cw,
    uint8_t* __restrict__ sout)
{
    __shared__ float ldsF[64 * 130];             // 33,280 B
    int bid0 = blockIdx.x;                       // 3200 = 16n x 40hy x 5wg
    int bid = (bid0 & 7) * 400 + (bid0 >> 3);    // XCD-contiguous
    int wg = bid % 5;
    int hy = (bid / 5) % 40;
    int n  = bid / 200;
    int tid = threadIdx.x;
    int wxl = tid >> 5, tt = tid & 31, t0 = tt * 4;
    int wx = wg * 8 + wxl;

    float4 tap[18];
    #pragma unroll
    for (int c = 0; c < 2; c++)
      #pragma unroll
      for (int dh = 0; dh < 3; dh++)
        #pragma unroll
        for (int dw = 0; dw < 3; dw++) {
            int q = c * 9 + dh * 3 + dw;
            int hh = hy + dh - 1, ww = wx + dw - 1;
            bool ok = (hh >= 0) && (hh < 40) && (ww >= 0) && (ww < 40);
            tap[q] = ok ? *(const float4*)(in +
                (((size_t)(n * 2 + c) * 40 + hh) * 40 + ww) * T + t0)
                        : make_float4(0.f, 0.f, 0.f, 0.f);
        }

    #pragma unroll
    for (int o = 0; o < 8; o++) {
        const float* wp = cw + o * 18;           // uniform -> s_load
        float a0 = 0.f, a1 = 0.f, a2 = 0.f, a3 = 0.f;
        #pragma unroll
        for (int q = 0; q < 18; q++) {
            a0 += wp[q] * tap[q].x;  a1 += wp[q] * tap[q].y;
            a2 += wp[q] * tap[q].z;  a3 += wp[q] * tap[q].w;
        }
        float* xr = &ldsF[(o * 8 + wxl) * 130 + t0];
        xr[0] = a0 * 20.0f; xr[1] = a1 * 20.0f;
        xr[2] = a2 * 20.0f; xr[3] = a3 * 20.0f;
    }
    __syncthreads();
    if (tid < 64) {
        int o = tid >> 3, wxl2 = tid & 7;
        float u = 0.f, v = 0.f;
        uint32_t ob[32];
        const float* xr = &ldsF[tid * 130];
        #pragma unroll
        for (int tb = 0; tb < 32; tb++) {
            float s0, s1, s2, s3;
            neuron_step(xr[tb * 4 + 0], u, v, s0);
            neuron_step(xr[tb * 4 + 1], u, v, s1);
            neuron_step(xr[tb * 4 + 2], u, v, s2);
            neuron_step(xr[tb * 4 + 3], u, v, s3);
            ob[tb] = (uint32_t)s0 | ((uint32_t)s1 << 8) |
                     ((uint32_t)s2 << 16) | ((uint32_t)s3 << 24);
        }
        uint32_t* op = (uint32_t*)(sout +
            (((size_t)(n * 8 + o) * 40 + hy) * 40 + wg * 8 + wxl2) * T);
        #pragma unroll
        for (int k = 0; k < 8; k++)
            *(uint4*)&op[k * 4] =
                make_uint4(ob[k*4], ob[k*4+1], ob[k*4+2], ob[k*4+3]);
    }
}

// ---------------- pool_pad: 2x2 sum + scan + delay -> sP bf16 directly ------
template<int C, int HO, int WO>
__global__ __launch_bounds__(320) void pool_pad(
    const uint8_t* __restrict__ in, const float* __restrict__ pw_ptr,
    uint16_t* __restrict__ sP)
{
    constexpr int CB = 320 / C;                  // cells per block (40 or 20)
    constexpr int GP = (HO * WO) / CB;           // cell-groups per n (10 or 5)
    __shared__ uint8_t raw[320 * 132];           // 42,240 B, two overlaid uses
    uint32_t* ldsF = (uint32_t*)raw;             // [320 rows][20 u32] staging
    uint8_t*  sbuf = raw;                        // [320 rows][132 B] spikes

    int bid = blockIdx.x;                        // 16n x GP
    int grp = bid % GP, n = bid / GP;
    int tid = threadIdx.x;
    float pw = pw_ptr[0];

    float u = 0.f, v = 0.f;
    uint32_t ob[32];
    uint32_t carry = 0;

    #pragma unroll
    for (int tb = 0; tb < 2; tb++) {
        __syncthreads();
        #pragma unroll
        for (int k = 0; k < 4; k++) {
            int f = tid + k * 320;
            int row = f >> 2, q = f & 3;
            int c = row / CB, p = row % CB;
            int hw = grp * CB + p;
            int wx = hw % WO, hy = hw / WO;
            const uint8_t* p00 = in +
                (((size_t)(n * C + c) * (2 * HO) + 2 * hy) * (2 * WO) + 2 * wx) * T;
            int off = tb * 64 + q * 16;
            uint4 a = *(const uint4*)(p00 + off);
            uint4 b = *(const uint4*)(p00 + T + off);
            uint4 cc = *(const uint4*)(p00 + 2 * WO * T + off);
            uint4 d = *(const uint4*)(p00 + 2 * WO * T + T + off);
            *(uint4*)&ldsF[row * 20 + q * 4] =
                make_uint4(a.x + b.x + cc.x + d.x, a.y + b.y + cc.y + d.y,
                           a.z + b.z + cc.z + d.z, a.w + b.w + cc.w + d.w);
        }
        __syncthreads();
        #pragma unroll
        for (int q = 0; q < 4; q++) {
            uint4 w = *(const uint4*)&ldsF[tid * 20 + q * 4];
            uint32_t words[4] = {w.x, w.y, w.z, w.w};
            #pragma unroll
            for (int j = 0; j < 4; j++) {
                uint32_t cur = words[j];
                uint32_t del = (cur << 8) | carry;   // delay_shift bytes
                carry = cur >> 24;
                float s0, s1, s2, s3;
                neuron_step(pw * (float)(del & 0xffu),         u, v, s0);
                neuron_step(pw * (float)((del >> 8) & 0xffu),  u, v, s1);
                neuron_step(pw * (float)((del >> 16) & 0xffu), u, v, s2);
                neuron_step(pw * (float)((del >> 24) & 0xffu), u, v, s3);
                ob[tb * 16 + q * 4 + j] = (uint32_t)s0 | ((uint32_t)s1 << 8) |
                                          ((uint32_t)s2 << 16) | ((uint32_t)s3 << 24);
            }
        }
    }

    // phase 3: spikes -> LDS byte rows (staging reads complete at barrier)
    __syncthreads();
    #pragma unroll
    for (int j = 0; j < 32; j++)
        *(uint32_t*)&sbuf[tid * 132 + j * 4] = ob[j];
    __syncthreads();

    // phase 4: transpose-write sP[cell][tau][16c], conv delay via tau-1
    constexpr int CHK = CB * 128;                // 32B chunks (5120 or 2560)
    #pragma unroll
    for (int k = 0; k < CHK / 320; k++) {
        int ci = k * 320 + tid;
        int p = ci >> 7, tau = ci & 127;
        int hw = grp * CB + p;
        int wx = hw % WO, hy = hw / WO;
        uint32_t wb[8];
        #pragma unroll
        for (int e = 0; e < 16; e += 2) {
            uint32_t lo = 0u, hi = 0u;
            if (tau >= 1) {
                if (e < C)     lo = sbuf[(e * CB + p) * 132 + tau - 1] ? 0x3F80u : 0u;
                if (e + 1 < C) hi = sbuf[((e + 1) * CB + p) * 132 + tau - 1] ? 0x3F80u : 0u;
            }
            wb[e >> 1] = lo | (hi << 16);
        }
        uint16_t* dst = sP + ((size_t)((n * (HO + 2) + hy + 1) * (WO + 2)
                                       + wx + 1)) * 2048 + tau * 16;
        *(uint4*)dst       = make_uint4(wb[0], wb[1], wb[2], wb[3]);
        *(uint4*)(dst + 8) = make_uint4(wb[4], wb[5], wb[6], wb[7]);
    }
}

// ---------------- prep: wsplit + apack_w + halo zeroing, one dispatch -------
__global__ __launch_bounds__(256) void prep(
    const float* __restrict__ fw, const float* __restrict__ c2w,
    const float* __restrict__ c3w, uint16_t* __restrict__ bs,
    uint16_t* __restrict__ apk, uint16_t* __restrict__ s2P,
    uint16_t* __restrict__ s4P)
{
    int bid = blockIdx.x;
    int tid = threadIdx.x;
    if (bid < 1600) {
        int i = bid * 256 + tid;                 // 409,600 threads, 4 elems
        float4 wv = *(const float4*)(fw + i * 4);
        float w4[4] = {wv.x, wv.y, wv.z, wv.w};
        uint16_t h[4], m[4], l[4];
        #pragma unroll
        for (int j = 0; j < 4; j++) {
            uint32_t b0 = __float_as_uint(w4[j]);
            h[j] = (uint16_t)(b0 >> 16);
            float r1 = w4[j] - __uint_as_float(b0 & 0xFFFF0000u);   // exact
            uint32_t b1 = __float_as_uint(r1);
            m[j] = (uint16_t)(b1 >> 16);
            float r2 = r1 - __uint_as_float(b1 & 0xFFFF0000u);      // exact
            l[j] = (uint16_t)(__float_as_uint(r2) >> 16);           // exact
        }
        *(ushort4*)(bs +       0 + i * 4) = make_ushort4(h[0], h[1], h[2], h[3]);
        *(ushort4*)(bs + 1638400 + i * 4) = make_ushort4(m[0], m[1], m[2], m[3]);
        *(ushort4*)(bs + 3276800 + i * 4) = make_ushort4(l[0], l[1], l[2], l[3]);
    } else if (bid < 1614) {
        int unit = (bid - 1600) * 4 + (tid >> 6);    // 0..55, 54 used
        if (unit >= 54) return;
        int conv = unit / 27;
        int plane = (unit % 27) / 9;
        int dlt = unit % 9;
        int lane = tid & 63;
        int o = lane & 31, chi = (lane >> 5) * 8;
        int CO = conv ? 32 : 16;
        int CI = conv ? 16 : 8;
        const float* Wp = conv ? c3w : c2w;
        uint32_t wb[4] = {0u, 0u, 0u, 0u};
        #pragma unroll
        for (int e = 0; e < 8; e++) {
            int c = chi + e;
            float w = (o < CO && c < CI) ? Wp[((size_t)o * CI + c) * 9 + dlt] : 0.f;
            uint32_t b0 = __float_as_uint(w);
            uint16_t hi = (uint16_t)(b0 >> 16);
            float r1 = w - __uint_as_float(b0 & 0xFFFF0000u);     // exact
            uint32_t b1 = __float_as_uint(r1);
            uint16_t md = (uint16_t)(b1 >> 16);
            float r2 = r1 - __uint_as_float(b1 & 0xFFFF0000u);    // exact
            uint16_t lo = (uint16_t)(__float_as_uint(r2) >> 16);  // exact
            uint32_t pv = (plane == 0) ? hi : ((plane == 1) ? md : lo);
            wb[e >> 1] |= pv << ((e & 1) * 16);
        }
        *(uint4*)(apk + ((size_t)conv * 27 + plane * 9 + dlt) * 512 + lane * 8) =
            make_uint4(wb[0], wb[1], wb[2], wb[3]);
    } else {
        int hid = bid - 1614;
        uint8_t* dst;
        if (hid < 1344) {                        // conv2 ring: 16n x 84
            int n = hid / 84, r = hid % 84;
            int hy, wx;
            if (r < 22)      { hy = 0;  wx = r; }
            else if (r < 44) { hy = 21; wx = r - 22; }
            else { int r2 = r - 44; hy = 1 + (r2 >> 1); wx = (r2 & 1) ? 21 : 0; }
            dst = (uint8_t*)s2P + ((size_t)(n * 484) + hy * 22 + wx) * 4096;
        } else {                                 // conv3 ring: 16n x 44
            int h2 = hid - 1344;
            int n = h2 / 44, r = h2 % 44;
            int hy, wx;
            if (r < 12)      { hy = 0;  wx = r; }
            else if (r < 24) { hy = 11; wx = r - 12; }
            else { int r2 = r - 24; hy = 1 + (r2 >> 1); wx = (r2 & 1) ? 11 : 0; }
            dst = (uint8_t*)s4P + ((size_t)(n * 144) + hy * 12 + wx) * 4096;
        }
        *(uint4*)(dst + tid * 16) = make_uint4(0u, 0u, 0u, 0u);
    }
}

// ---------------- conv_scan_mfma: MFMA conv + in-block LIF scan -------------
// Block = 256 thr (4 waves = 4 tau-chunks) x PB positions, all COUT, all T.
// R17: PB halved -> LDS 33,280 B -> 4 blocks/CU, 4 waves/SIMD.
template<int COUT, int PB, int H, int W>
__global__ __launch_bounds__(256, 2) void conv_scan_mfma(
    const uint16_t* __restrict__ sP, const uint16_t* __restrict__ apk,
    float scale, uint8_t* __restrict__ sout)
{
    constexpr int ROWS = COUT * PB;              // 64
    __shared__ float ldsF[ROWS * 130];           // 33,280 B
    constexpr int HW = H * W;
    constexpr int GP = HW / PB;
    int per = (16 * GP) >> 3;                    // blocks per XCD
    int vbid = (blockIdx.x & 7) * per + (blockIdx.x >> 3);
    int n = vbid / GP, grp = vbid % GP;
    int tid = threadIdx.x;
    int wv = tid >> 6, lane = tid & 63;
    int l31 = lane & 31, lhi = lane >> 5;
    int t0 = wv * 32;

    const uint16_t* ap = apk + (size_t)lane * 8;
    v8s a0[9], a1[9], a2[9];
    #pragma unroll
    for (int d = 0; d < 9; d++) {
        a0[d] = *(const v8s*)(ap + d * 512);
        a1[d] = *(const v8s*)(ap + (9 + d) * 512);
        a2[d] = *(const v8s*)(ap + (18 + d) * 512);
    }

    #pragma unroll
    for (int p = 0; p < PB; p++) {
        int hw = grp * PB + p;
        int hy = hw / W, wx = hw % W;
        v8s bfr[9];
        #pragma unroll
        for (int d = 0; d < 9; d++) {
            int dh = d / 3, dw = d % 3;
            const uint16_t* src = sP
                + ((size_t)((n * (H + 2) + hy + dh) * (W + 2) + wx + dw)) * 2048
                + (t0 + l31) * 16 + lhi * 8;
            bfr[d] = *(const v8s*)src;
        }
        v16f ac0, ac1, ac2;
        #pragma unroll
        for (int e = 0; e < 16; e++) { ac0[e] = 0.f; ac1[e] = 0.f; ac2[e] = 0.f; }
        #pragma unroll
        for (int d = 0; d < 9; d++) {
            ac0 = __builtin_amdgcn_mfma_f32_32x32x16_bf16(a0[d], bfr[d], ac0, 0, 0, 0);
            ac1 = __builtin_amdgcn_mfma_f32_32x32x16_bf16(a1[d], bfr[d], ac1, 0, 0, 0);
            ac2 = __builtin_amdgcn_mfma_f32_32x32x16_bf16(a2[d], bfr[d], ac2, 0, 0, 0);
        }
        constexpr int NR = (COUT == 32) ? 16 : 8;
        #pragma unroll
        for (int r = 0; r < NR; r++) {
            int o = (r & 3) + 8 * (r >> 2) + 4 * lhi;
            ldsF[(o * PB + p) * 130 + t0 + l31] =
                (ac0[r] + ac1[r] + ac2[r]) * scale;
        }
    }
    __syncthreads();
    if (tid < ROWS) {
        int o = tid / PB, p = tid % PB;
        int hw = grp * PB + p;
        float u = 0.f, v = 0.f;
        uint32_t ob[32];
        const float* xr = &ldsF[tid * 130];
        #pragma unroll
        for (int tb = 0; tb < 32; tb++) {
            float2 xa = *(const float2*)(xr + tb * 4);
            float2 xb = *(const float2*)(xr + tb * 4 + 2);
            float s0, s1, s2, s3;
            neuron_step(xa.x, u, v, s0); neuron_step(xa.y, u, v, s1);
            neuron_step(xb.x, u, v, s2); neuron_step(xb.y, u, v, s3);
            ob[tb] = (uint32_t)s0 | ((uint32_t)s1 << 8) |
                     ((uint32_t)s2 << 16) | ((uint32_t)s3 << 24);
        }
        uint32_t* op = (uint32_t*)(sout + ((size_t)(n * COUT + o) * HW + hw) * 128);
        #pragma unroll
        for (int k = 0; k < 8; k++)
            *(uint4*)&op[k * 4] =
                make_uint4(ob[k*4], ob[k*4+1], ob[k*4+2], ob[k*4+3]);
    }
}

// ---------------- sT: s5 u8 [16][3200][128] -> At bf16 [16][128][3200] ------
__global__ __launch_bounds__(256) void sT_bf16(
    const uint8_t* __restrict__ s5, uint16_t* __restrict__ At)
{
    __shared__ uint8_t tile[64 * 132];           // 64 c-rows x 128 t (+4 pad)
    int bid = blockIdx.x;                        // 800 = 16 n x 50 chunks
    int n = bid / 50;
    int c0 = (bid % 50) * 64;
    int tid = threadIdx.x;
    {
        int row = tid >> 2, q = tid & 3;
        const uint8_t* src = s5 + ((size_t)(n * 3200 + c0 + row)) * T + q * 32;
        *(uint4*)&tile[row * 132 + q * 32]      = *(const uint4*)src;
        *(uint4*)&tile[row * 132 + q * 32 + 16] = *(const uint4*)(src + 16);
    }
    __syncthreads();
    int t = tid >> 1, half = tid & 1;
    uint32_t wb[16];
    if (t == 0) {
        #pragma unroll
        for (int j = 0; j < 16; j++) wb[j] = 0u;
    } else {
        #pragma unroll
        for (int j = 0; j < 16; j++) {
            uint32_t lo = tile[(half * 32 + 2 * j) * 132 + (t - 1)] ? 0x3F80u : 0u;
            uint32_t hi = tile[(half * 32 + 2 * j + 1) * 132 + (t - 1)] ? 0x3F80u : 0u;
            wb[j] = lo | (hi << 16);
        }
    }
    uint16_t* dst = At + ((size_t)(n * 128 + t)) * 3200 + c0 + half * 32;
    #pragma unroll
    for (int k = 0; k < 4; k++)
        *(uint4*)(dst + k * 8) = make_uint4(wb[k*4], wb[k*4+1], wb[k*4+2], wb[k*4+3]);
}

// ---------------- FC GEMM on matrix cores (8 waves, 2x4 split) --------------
#define GLDS16(g, s) __builtin_amdgcn_global_load_lds( \
    (const __attribute__((address_space(1))) uint32_t*)(g), \
    (__attribute__((address_space(3))) uint32_t*)(s), 16, 0, 0)

__global__ __launch_bounds__(512, 4) void fc_gemm_mfma(
    const uint16_t* __restrict__ At,   // [16][128][3200] bf16
    const uint16_t* __restrict__ Bs,   // [3][512][3200] bf16
    float* __restrict__ ypart)         // [10][16][128][512] f32
{
    __shared__ uint8_t lds[65536];     // A [128][64]bf16 @0; B 3x[128][64] @16K
    int bid0 = blockIdx.x;             // 640 = 10ks x 4ob x 16n (n fastest)
    int bid = (bid0 & 7) * 80 + (bid0 >> 3);     // XCD-contiguous
    int n  = bid & 15;
    int ob = (bid >> 4) & 3;
    int ks = bid >> 6;
    int o0 = ob * 128;
    int cbase = ks * 320;

    int tid = threadIdx.x;
    int w8 = tid >> 6;                 // wave 0..7
    int wm = w8 >> 2;                  // t-half
    int wn = w8 & 3;                   // o-quarter
    int lane = tid & 63;
    int l31 = lane & 31;
    int lhi = lane >> 5;               // k-half within frag
    int rb = lane >> 3;                // staging: row-in-8
    int gsw = (lane & 7) ^ (rb & 7);   // pre-swizzled source granule

    v16f acc[2];
    #pragma unroll
    for (int mi = 0; mi < 2; mi++)
        #pragma unroll
        for (int e = 0; e < 16; e++) acc[mi][e] = 0.0f;

    const uint16_t* Abase = At + (size_t)(n * 128) * 3200 + gsw * 8;

    for (int kc = 0; kc < 5; kc++) {
        int c0 = cbase + kc * 64;
        // ---- stage A: 16 x 1KB chunks, chunk cid = i*8 + w8 ----
        #pragma unroll
        for (int i = 0; i < 2; i++) {
            int cid = i * 8 + w8;
            const uint16_t* src = Abase + (size_t)(cid * 8 + rb) * 3200 + c0;
            GLDS16(src, lds + cid * 1024);
        }
        // ---- stage B: 48 x 1KB chunks ----
        #pragma unroll
        for (int j = 0; j < 6; j++) {
            int cid = j * 8 + w8;
            int f0 = cid * 1024;
            int s = f0 >> 14;                    // split plane
            int r = ((f0 & 16383) >> 7) + rb;    // o-local row
            const uint16_t* src = Bs + (size_t)(s * 512 + o0 + r) * 3200
                                     + c0 + gsw * 8;
            GLDS16(src, lds + 16384 + f0);
        }
        __syncthreads();                         // drains vmcnt before barrier
        // ---- compute: 4 kf x (3 splits x 2 mi) MFMA per wave ----
        #pragma unroll
        for (int kf = 0; kf < 4; kf++) {
            int gc = kf * 2 + lhi;
            v8s av[2];
            #pragma unroll
            for (int mi = 0; mi < 2; mi++) {
                int t = wm * 64 + mi * 32 + l31;
                av[mi] = *(const v8s*)(lds + t * 128 + ((gc ^ (t & 7)) << 4));
            }
            #pragma unroll
            for (int s = 0; s < 3; s++) {
                int r = wn * 32 + l31;
                v8s bv = *(const v8s*)(lds + 16384 + s * 16384 + r * 128
                                       + ((gc ^ (r & 7)) << 4));
                #pragma unroll
                for (int mi = 0; mi < 2; mi++)
                    acc[mi] = __builtin_amdgcn_mfma_f32_32x32x16_bf16(
                        av[mi], bv, acc[mi], 0, 0, 0);
            }
        }
        __syncthreads();                         // LDS safe before next stage
    }
    // ---- epilogue: C/D layout col=lane&31, row=(r&3)+8*(r>>2)+4*(lane>>5) --
    float* yp = ypart + (size_t)ks * 1048576 + (size_t)n * 65536;
    int o = o0 + wn * 32 + l31;
    #pragma unroll
    for (int mi = 0; mi < 2; mi++) {
        #pragma unroll
        for (int r = 0; r < 16; r++) {
            int trow = wm * 64 + mi * 32 + (r & 3) + 8 * (r >> 2) + 4 * lhi;
            yp[trow * 512 + o] = acc[mi][r];
        }
    }
}

// ---------------- FC scan: fused 10-way partial reduce + LIF + delay --------
// Sum order k=0..9 identical to the old fc_reduce -> bitwise-same input.
__global__ __launch_bounds__(64) void fc_scan(
    const float* __restrict__ yp,     // [10][16][128][512]
    float* __restrict__ out)          // [16][512][128]
{
    int id = blockIdx.x * 64 + threadIdx.x;           // 8192
    int o = id & 511;
    int n = id >> 9;
    const float* base = yp + (size_t)n * 65536 + o;
    float u = 0.f, v = 0.f;
    float prev = 0.f;                 // final delay_shift
    for (int tb = 0; tb < T / 4; tb++) {
        float b[4];
        #pragma unroll
        for (int j = 0; j < 4; j++) {
            int t = tb * 4 + j;
            float x = base[(size_t)t * 512];
            #pragma unroll
            for (int k = 1; k < 10; k++)
                x += base[(size_t)k * 1048576 + (size_t)t * 512];
            float s;
            neuron_step(x, u, v, s);
            b[j] = prev; prev = s;
        }
        *(float4*)&out[((size_t)(n * 512 + o)) * T + tb * 4] =
            make_float4(b[0], b[1], b[2], b[3]);
    }
}

// ---------------- launch ----------------------------------------------------
extern "C" void kernel_launch(void* const* d_in, const int* in_sizes, int n_in,
                              void* d_out, int out_size, void* d_ws, size_t ws_size,
                              hipStream_t stream) {
    const float* spike = (const float*)d_in[0];   // [16][2][40][40][128]
    const float* c1w   = (const float*)d_in[1];   // [8][2][3][3]
    const float* c2w   = (const float*)d_in[2];   // [16][8][3][3]
    const float* c3w   = (const float*)d_in[3];   // [32][16][3][3]
    const float* p1w   = (const float*)d_in[4];   // scalar
    const float* p2w   = (const float*)d_in[5];   // scalar
    const float* fcw   = (const float*)d_in[6];   // [512][3200]
    float* out = (float*)d_out;                   // [16][512][128]

    char* ws = (char*)d_ws;
    // Lifetime-ordered map (ysum bounce deleted; max 151,967,744):
    uint8_t*  s1    = (uint8_t*)(ws);             // -> 26,214,400
    uint16_t* Bs16  = (uint16_t*)(ws + 26214400); // -> 36,044,800 (alive->fc)
    uint16_t* Apk   = (uint16_t*)(ws + 36044800); // -> 36,100,096 (alive->conv3)
    uint16_t* s2P   = (uint16_t*)(ws + 36100096); // -> 67,819,520
    uint8_t*  s3    = (uint8_t*)(ws + 67819520);  // -> 80,926,720
    uint16_t* s4P   = (uint16_t*)(ws + 80926720); // -> 90,363,904
    uint8_t*  s5    = (uint8_t*)(ws + 90363904);  // -> 96,917,504
    uint16_t* At16  = (uint16_t*)(ws + 96917504); // -> 110,024,704
    float*    ypart = (float*)(ws + 110024704);   // -> 151,967,744

    prep<<<3662, 256, 0, stream>>>(fcw, c2w, c3w, Bs16, Apk, s2P, s4P);
    conv1_scan<<<3200, 256, 0, stream>>>(spike, c1w, s1);

    pool_pad<8, 20, 20><<<160, 320, 0, stream>>>(s1, p1w, s2P);
    conv_scan_mfma<16, 4, 20, 20><<<1600, 256, 0, stream>>>(s2P, Apk, 100.0f, s3);

    pool_pad<16, 10, 10><<<80, 320, 0, stream>>>(s3, p2w, s4P);
    conv_scan_mfma<32, 2, 10, 10><<<800, 256, 0, stream>>>(s4P, Apk + 13824, 100.0f, s5);

    sT_bf16<<<800, 256, 0, stream>>>(s5, At16);
    fc_gemm_mfma<<<640, 512, 0, stream>>>(At16, Bs16, ypart);
    fc_scan<<<128, 64, 0, stream>>>(ypart, out);
}

// Round 13
// 240.771 us; speedup vs baseline: 1.2618x; 1.0193x over previous
//
#include <hip/hip_runtime.h>
#include <stdint.h>

// SNN forward: prep -> conv1+scan(fused) -> pool1+pad(fused) -> conv2+scan
// (MFMA) -> pool2+pad(fused) -> conv3+scan(MFMA) -> sT -> fc(MFMA) ->
// fc_scan(fused 10-way reduce + LIF + delay, wide-parallel).
// Neuron: u=.75u+x; v=.96875v+u; s=(v>=100); v*=(1-s). Spikes u8 in d_ws.
// R9:  FC GEMM on matrix cores (exact 3-way bf16 weight split).
// R11: conv2/conv3 on matrix cores via pre-padded/delayed sP + A-frag weights.
// R12: scan fused INTO the MFMA convs; XCD-contiguous block swizzle.
// R13: conv1+scan fused; R14: XCD swizzles + pool_pad; R15: fc 8-wave + prep.
// R17: conv_scan_mfma PB halved -> 4 blocks/CU (confirmed 244us, best).
// R18/R19: conv1_scan restructures regressed -> R17 version kept.
// R20: fc_reduce folded into fc_scan -- NEUTRAL: traffic saved but the
// fused kernel read 42MB with 8192 threads (0.5 waves/CU, latency-bound).
// R21: fc_scan rebuilt wide: 512 blocks x 256 thr; all 256 threads compute
// the k-ascending sums for 16 rows x 128 t into LDS [16][132] (2-way-free),
// then 16 threads scan. Same sum order + neuron sequence -> bitwise-same
// output; 16x thread-parallelism on the 42MB read. Single-variable round.

#define T 128
#define AI 0.75f
#define AV 0.96875f
#define THETA 100.0f

typedef __attribute__((ext_vector_type(8))) short v8s;    // 8 x bf16 bits
typedef __attribute__((ext_vector_type(16))) float v16f;  // 32x32 acc

__device__ __forceinline__ void neuron_step(float x, float& u, float& v, float& s) {
    u = AI * u + x;
    v = AV * v + u;
    s = (v >= THETA) ? 1.0f : 0.0f;
    v = v * (1.0f - s);
}

// ---------------- conv1 + scan fused: spikes fp32 -> s1 u8 (R17 version) ----
// Block = (n, hy, 8-wx group); 256 thr = 8 wx x 32 t-threads.
// Phase 1: x[o][wx][t] -> LDS (FMA order identical to old conv1_x).
// Phase 2: 64 threads scan one (o,wx) row each over t, write u8 spikes.
__global__ __launch_bounds__(256) void conv1_scan(
    const float* __restrict__ in, const float* __restrict__ cw,
    uint8_t* __restrict__ sout)
{
    __shared__ float ldsF[64 * 130];             // 33,280 B
    int bid0 = blockIdx.x;                       // 3200 = 16n x 40hy x 5wg
    int bid = (bid0 & 7) * 400 + (bid0 >> 3);    // XCD-contiguous
    int wg = bid % 5;
    int hy = (bid / 5) % 40;
    int n  = bid / 200;
    int tid = threadIdx.x;
    int wxl = tid >> 5, tt = tid & 31, t0 = tt * 4;
    int wx = wg * 8 + wxl;

    float4 tap[18];
    #pragma unroll
    for (int c = 0; c < 2; c++)
      #pragma unroll
      for (int dh = 0; dh < 3; dh++)
        #pragma unroll
        for (int dw = 0; dw < 3; dw++) {
            int q = c * 9 + dh * 3 + dw;
            int hh = hy + dh - 1, ww = wx + dw - 1;
            bool ok = (hh >= 0) && (hh < 40) && (ww >= 0) && (ww < 40);
            tap[q] = ok ? *(const float4*)(in +
                (((size_t)(n * 2 + c) * 40 + hh) * 40 + ww) * T + t0)
                        : make_float4(0.f, 0.f, 0.f, 0.f);
        }

    #pragma unroll
    for (int o = 0; o < 8; o++) {
        const float* wp = cw + o * 18;           // uniform -> s_load
        float a0 = 0.f, a1 = 0.f, a2 = 0.f, a3 = 0.f;
        #pragma unroll
        for (int q = 0; q < 18; q++) {
            a0 += wp[q] * tap[q].x;  a1 += wp[q] * tap[q].y;
            a2 += wp[q] * tap[q].z;  a3 += wp[q] * tap[q].w;
        }
        float* xr = &ldsF[(o * 8 + wxl) * 130 + t0];
        xr[0] = a0 * 20.0f; xr[1] = a1 * 20.0f;
        xr[2] = a2 * 20.0f; xr[3] = a3 * 20.0f;
    }
    __syncthreads();
    if (tid < 64) {
        int o = tid >> 3, wxl2 = tid & 7;
        float u = 0.f, v = 0.f;
        uint32_t ob[32];
        const float* xr = &ldsF[tid * 130];
        #pragma unroll
        for (int tb = 0; tb < 32; tb++) {
            float s0, s1, s2, s3;
            neuron_step(xr[tb * 4 + 0], u, v, s0);
            neuron_step(xr[tb * 4 + 1], u, v, s1);
            neuron_step(xr[tb * 4 + 2], u, v, s2);
            neuron_step(xr[tb * 4 + 3], u, v, s3);
            ob[tb] = (uint32_t)s0 | ((uint32_t)s1 << 8) |
                     ((uint32_t)s2 << 16) | ((uint32_t)s3 << 24);
        }
        uint32_t* op = (uint32_t*)(sout +
            (((size_t)(n * 8 + o) * 40 + hy) * 40 + wg * 8 + wxl2) * T);
        #pragma unroll
        for (int k = 0; k < 8; k++)
            *(uint4*)&op[k * 4] =
                make_uint4(ob[k*4], ob[k*4+1], ob[k*4+2], ob[k*4+3]);
    }
}

// ---------------- pool_pad: 2x2 sum + scan + delay -> sP bf16 directly ------
template<int C, int HO, int WO>
__global__ __launch_bounds__(320) void pool_pad(
    const uint8_t* __restrict__ in, const float* __restrict__ pw_ptr,
    uint16_t* __restrict__ sP)
{
    constexpr int CB = 320 / C;                  // cells per block (40 or 20)
    constexpr int GP = (HO * WO) / CB;           // cell-groups per n (10 or 5)
    __shared__ uint8_t raw[320 * 132];           // 42,240 B, two overlaid uses
    uint32_t* ldsF = (uint32_t*)raw;             // [320 rows][20 u32] staging
    uint8_t*  sbuf = raw;                        // [320 rows][132 B] spikes

    int bid = blockIdx.x;                        // 16n x GP
    int grp = bid % GP, n = bid / GP;
    int tid = threadIdx.x;
    float pw = pw_ptr[0];

    float u = 0.f, v = 0.f;
    uint32_t ob[32];
    uint32_t carry = 0;

    #pragma unroll
    for (int tb = 0; tb < 2; tb++) {
        __syncthreads();
        #pragma unroll
        for (int k = 0; k < 4; k++) {
            int f = tid + k * 320;
            int row = f >> 2, q = f & 3;
            int c = row / CB, p = row % CB;
            int hw = grp * CB + p;
            int wx = hw % WO, hy = hw / WO;
            const uint8_t* p00 = in +
                (((size_t)(n * C + c) * (2 * HO) + 2 * hy) * (2 * WO) + 2 * wx) * T;
            int off = tb * 64 + q * 16;
            uint4 a = *(const uint4*)(p00 + off);
            uint4 b = *(const uint4*)(p00 + T + off);
            uint4 cc = *(const uint4*)(p00 + 2 * WO * T + off);
            uint4 d = *(const uint4*)(p00 + 2 * WO * T + T + off);
            *(uint4*)&ldsF[row * 20 + q * 4] =
                make_uint4(a.x + b.x + cc.x + d.x, a.y + b.y + cc.y + d.y,
                           a.z + b.z + cc.z + d.z, a.w + b.w + cc.w + d.w);
        }
        __syncthreads();
        #pragma unroll
        for (int q = 0; q < 4; q++) {
            uint4 w = *(const uint4*)&ldsF[tid * 20 + q * 4];
            uint32_t words[4] = {w.x, w.y, w.z, w.w};
            #pragma unroll
            for (int j = 0; j < 4; j++) {
                uint32_t cur = words[j];
                uint32_t del = (cur << 8) | carry;   // delay_shift bytes
                carry = cur >> 24;
                float s0, s1, s2, s3;
                neuron_step(pw * (float)(del & 0xffu),         u, v, s0);
                neuron_step(pw * (float)((del >> 8) & 0xffu),  u, v, s1);
                neuron_step(pw * (float)((del >> 16) & 0xffu), u, v, s2);
                neuron_step(pw * (float)((del >> 24) & 0xffu), u, v, s3);
                ob[tb * 16 + q * 4 + j] = (uint32_t)s0 | ((uint32_t)s1 << 8) |
                                          ((uint32_t)s2 << 16) | ((uint32_t)s3 << 24);
            }
        }
    }

    // phase 3: spikes -> LDS byte rows (staging reads complete at barrier)
    __syncthreads();
    #pragma unroll
    for (int j = 0; j < 32; j++)
        *(uint32_t*)&sbuf[tid * 132 + j * 4] = ob[j];
    __syncthreads();

    // phase 4: transpose-write sP[cell][tau][16c], conv delay via tau-1
    constexpr int CHK = CB * 128;                // 32B chunks (5120 or 2560)
    #pragma unroll
    for (int k = 0; k < CHK / 320; k++) {
        int ci = k * 320 + tid;
        int p = ci >> 7, tau = ci & 127;
        int hw = grp * CB + p;
        int wx = hw % WO, hy = hw / WO;
        uint32_t wb[8];
        #pragma unroll
        for (int e = 0; e < 16; e += 2) {
            uint32_t lo = 0u, hi = 0u;
            if (tau >= 1) {
                if (e < C)     lo = sbuf[(e * CB + p) * 132 + tau - 1] ? 0x3F80u : 0u;
                if (e + 1 < C) hi = sbuf[((e + 1) * CB + p) * 132 + tau - 1] ? 0x3F80u : 0u;
            }
            wb[e >> 1] = lo | (hi << 16);
        }
        uint16_t* dst = sP + ((size_t)((n * (HO + 2) + hy + 1) * (WO + 2)
                                       + wx + 1)) * 2048 + tau * 16;
        *(uint4*)dst       = make_uint4(wb[0], wb[1], wb[2], wb[3]);
        *(uint4*)(dst + 8) = make_uint4(wb[4], wb[5], wb[6], wb[7]);
    }
}

// ---------------- prep: wsplit + apack_w + halo zeroing, one dispatch -------
__global__ __launch_bounds__(256) void prep(
    const float* __restrict__ fw, const float* __restrict__ c2w,
    const float* __restrict__ c3w, uint16_t* __restrict__ bs,
    uint16_t* __restrict__ apk, uint16_t* __restrict__ s2P,
    uint16_t* __restrict__ s4P)
{
    int bid = blockIdx.x;
    int tid = threadIdx.x;
    if (bid < 1600) {
        int i = bid * 256 + tid;                 // 409,600 threads, 4 elems
        float4 wv = *(const float4*)(fw + i * 4);
        float w4[4] = {wv.x, wv.y, wv.z, wv.w};
        uint16_t h[4], m[4], l[4];
        #pragma unroll
        for (int j = 0; j < 4; j++) {
            uint32_t b0 = __float_as_uint(w4[j]);
            h[j] = (uint16_t)(b0 >> 16);
            float r1 = w4[j] - __uint_as_float(b0 & 0xFFFF0000u);   // exact
            uint32_t b1 = __float_as_uint(r1);
            m[j] = (uint16_t)(b1 >> 16);
            float r2 = r1 - __uint_as_float(b1 & 0xFFFF0000u);      // exact
            l[j] = (uint16_t)(__float_as_uint(r2) >> 16);           // exact
        }
        *(ushort4*)(bs +       0 + i * 4) = make_ushort4(h[0], h[1], h[2], h[3]);
        *(ushort4*)(bs + 1638400 + i * 4) = make_ushort4(m[0], m[1], m[2], m[3]);
        *(ushort4*)(bs + 3276800 + i * 4) = make_ushort4(l[0], l[1], l[2], l[3]);
    } else if (bid < 1614) {
        int unit = (bid - 1600) * 4 + (tid >> 6);    // 0..55, 54 used
        if (unit >= 54) return;
        int conv = unit / 27;
        int plane = (unit % 27) / 9;
        int dlt = unit % 9;
        int lane = tid & 63;
        int o = lane & 31, chi = (lane >> 5) * 8;
        int CO = conv ? 32 : 16;
        int CI = conv ? 16 : 8;
        const float* Wp = conv ? c3w : c2w;
        uint32_t wb[4] = {0u, 0u, 0u, 0u};
        #pragma unroll
        for (int e = 0; e < 8; e++) {
            int c = chi + e;
            float w = (o < CO && c < CI) ? Wp[((size_t)o * CI + c) * 9 + dlt] : 0.f;
            uint32_t b0 = __float_as_uint(w);
            uint16_t hi = (uint16_t)(b0 >> 16);
            float r1 = w - __uint_as_float(b0 & 0xFFFF0000u);     // exact
            uint32_t b1 = __float_as_uint(r1);
            uint16_t md = (uint16_t)(b1 >> 16);
            float r2 = r1 - __uint_as_float(b1 & 0xFFFF0000u);    // exact
            uint16_t lo = (uint16_t)(__float_as_uint(r2) >> 16);  // exact
            uint32_t pv = (plane == 0) ? hi : ((plane == 1) ? md : lo);
            wb[e >> 1] |= pv << ((e & 1) * 16);
        }
        *(uint4*)(apk + ((size_t)conv * 27 + plane * 9 + dlt) * 512 + lane * 8) =
            make_uint4(wb[0], wb[1], wb[2], wb[3]);
    } else {
        int hid = bid - 1614;
        uint8_t* dst;
        if (hid < 1344) {                        // conv2 ring: 16n x 84
            int n = hid / 84, r = hid % 84;
            int hy, wx;
            if (r < 22)      { hy = 0;  wx = r; }
            else if (r < 44) { hy = 21; wx = r - 22; }
            else { int r2 = r - 44; hy = 1 + (r2 >> 1); wx = (r2 & 1) ? 21 : 0; }
            dst = (uint8_t*)s2P + ((size_t)(n * 484) + hy * 22 + wx) * 4096;
        } else {                                 // conv3 ring: 16n x 44
            int h2 = hid - 1344;
            int n = h2 / 44, r = h2 % 44;
            int hy, wx;
            if (r < 12)      { hy = 0;  wx = r; }
            else if (r < 24) { hy = 11; wx = r - 12; }
            else { int r2 = r - 24; hy = 1 + (r2 >> 1); wx = (r2 & 1) ? 11 : 0; }
            dst = (uint8_t*)s4P + ((size_t)(n * 144) + hy * 12 + wx) * 4096;
        }
        *(uint4*)(dst + tid * 16) = make_uint4(0u, 0u, 0u, 0u);
    }
}

// ---------------- conv_scan_mfma: MFMA conv + in-block LIF scan -------------
// Block = 256 thr (4 waves = 4 tau-chunks) x PB positions, all COUT, all T.
// R17: PB halved -> LDS 33,280 B -> 4 blocks/CU, 4 waves/SIMD.
template<int COUT, int PB, int H, int W>
__global__ __launch_bounds__(256, 2) void conv_scan_mfma(
    const uint16_t* __restrict__ sP, const uint16_t* __restrict__ apk,
    float scale, uint8_t* __restrict__ sout)
{
    constexpr int ROWS = COUT * PB;              // 64
    __shared__ float ldsF[ROWS * 130];           // 33,280 B
    constexpr int HW = H * W;
    constexpr int GP = HW / PB;
    int per = (16 * GP) >> 3;                    // blocks per XCD
    int vbid = (blockIdx.x & 7) * per + (blockIdx.x >> 3);
    int n = vbid / GP, grp = vbid % GP;
    int tid = threadIdx.x;
    int wv = tid >> 6, lane = tid & 63;
    int l31 = lane & 31, lhi = lane >> 5;
    int t0 = wv * 32;

    const uint16_t* ap = apk + (size_t)lane * 8;
    v8s a0[9], a1[9], a2[9];
    #pragma unroll
    for (int d = 0; d < 9; d++) {
        a0[d] = *(const v8s*)(ap + d * 512);
        a1[d] = *(const v8s*)(ap + (9 + d) * 512);
        a2[d] = *(const v8s*)(ap + (18 + d) * 512);
    }

    #pragma unroll
    for (int p = 0; p < PB; p++) {
        int hw = grp * PB + p;
        int hy = hw / W, wx = hw % W;
        v8s bfr[9];
        #pragma unroll
        for (int d = 0; d < 9; d++) {
            int dh = d / 3, dw = d % 3;
            const uint16_t* src = sP
                + ((size_t)((n * (H + 2) + hy + dh) * (W + 2) + wx + dw)) * 2048
                + (t0 + l31) * 16 + lhi * 8;
            bfr[d] = *(const v8s*)src;
        }
        v16f ac0, ac1, ac2;
        #pragma unroll
        for (int e = 0; e < 16; e++) { ac0[e] = 0.f; ac1[e] = 0.f; ac2[e] = 0.f; }
        #pragma unroll
        for (int d = 0; d < 9; d++) {
            ac0 = __builtin_amdgcn_mfma_f32_32x32x16_bf16(a0[d], bfr[d], ac0, 0, 0, 0);
            ac1 = __builtin_amdgcn_mfma_f32_32x32x16_bf16(a1[d], bfr[d], ac1, 0, 0, 0);
            ac2 = __builtin_amdgcn_mfma_f32_32x32x16_bf16(a2[d], bfr[d], ac2, 0, 0, 0);
        }
        constexpr int NR = (COUT == 32) ? 16 : 8;
        #pragma unroll
        for (int r = 0; r < NR; r++) {
            int o = (r & 3) + 8 * (r >> 2) + 4 * lhi;
            ldsF[(o * PB + p) * 130 + t0 + l31] =
                (ac0[r] + ac1[r] + ac2[r]) * scale;
        }
    }
    __syncthreads();
    if (tid < ROWS) {
        int o = tid / PB, p = tid % PB;
        int hw = grp * PB + p;
        float u = 0.f, v = 0.f;
        uint32_t ob[32];
        const float* xr = &ldsF[tid * 130];
        #pragma unroll
        for (int tb = 0; tb < 32; tb++) {
            float2 xa = *(const float2*)(xr + tb * 4);
            float2 xb = *(const float2*)(xr + tb * 4 + 2);
            float s0, s1, s2, s3;
            neuron_step(xa.x, u, v, s0); neuron_step(xa.y, u, v, s1);
            neuron_step(xb.x, u, v, s2); neuron_step(xb.y, u, v, s3);
            ob[tb] = (uint32_t)s0 | ((uint32_t)s1 << 8) |
                     ((uint32_t)s2 << 16) | ((uint32_t)s3 << 24);
        }
        uint32_t* op = (uint32_t*)(sout + ((size_t)(n * COUT + o) * HW + hw) * 128);
        #pragma unroll
        for (int k = 0; k < 8; k++)
            *(uint4*)&op[k * 4] =
                make_uint4(ob[k*4], ob[k*4+1], ob[k*4+2], ob[k*4+3]);
    }
}

// ---------------- sT: s5 u8 [16][3200][128] -> At bf16 [16][128][3200] ------
__global__ __launch_bounds__(256) void sT_bf16(
    const uint8_t* __restrict__ s5, uint16_t* __restrict__ At)
{
    __shared__ uint8_t tile[64 * 132];           // 64 c-rows x 128 t (+4 pad)
    int bid = blockIdx.x;                        // 800 = 16 n x 50 chunks
    int n = bid / 50;
    int c0 = (bid % 50) * 64;
    int tid = threadIdx.x;
    {
        int row = tid >> 2, q = tid & 3;
        const uint8_t* src = s5 + ((size_t)(n * 3200 + c0 + row)) * T + q * 32;
        *(uint4*)&tile[row * 132 + q * 32]      = *(const uint4*)src;
        *(uint4*)&tile[row * 132 + q * 32 + 16] = *(const uint4*)(src + 16);
    }
    __syncthreads();
    int t = tid >> 1, half = tid & 1;
    uint32_t wb[16];
    if (t == 0) {
        #pragma unroll
        for (int j = 0; j < 16; j++) wb[j] = 0u;
    } else {
        #pragma unroll
        for (int j = 0; j < 16; j++) {
            uint32_t lo = tile[(half * 32 + 2 * j) * 132 + (t - 1)] ? 0x3F80u : 0u;
            uint32_t hi = tile[(half * 32 + 2 * j + 1) * 132 + (t - 1)] ? 0x3F80u : 0u;
            wb[j] = lo | (hi << 16);
        }
    }
    uint16_t* dst = At + ((size_t)(n * 128 + t)) * 3200 + c0 + half * 32;
    #pragma unroll
    for (int k = 0; k < 4; k++)
        *(uint4*)(dst + k * 8) = make_uint4(wb[k*4], wb[k*4+1], wb[k*4+2], wb[k*4+3]);
}

// ---------------- FC GEMM on matrix cores (8 waves, 2x4 split) --------------
#define GLDS16(g, s) __builtin_amdgcn_global_load_lds( \
    (const __attribute__((address_space(1))) uint32_t*)(g), \
    (__attribute__((address_space(3))) uint32_t*)(s), 16, 0, 0)

__global__ __launch_bounds__(512, 4) void fc_gemm_mfma(
    const uint16_t* __restrict__ At,   // [16][128][3200] bf16
    const uint16_t* __restrict__ Bs,   // [3][512][3200] bf16
    float* __restrict__ ypart)         // [10][16][128][512] f32
{
    __shared__ uint8_t lds[65536];     // A [128][64]bf16 @0; B 3x[128][64] @16K
    int bid0 = blockIdx.x;             // 640 = 10ks x 4ob x 16n (n fastest)
    int bid = (bid0 & 7) * 80 + (bid0 >> 3);     // XCD-contiguous
    int n  = bid & 15;
    int ob = (bid >> 4) & 3;
    int ks = bid >> 6;
    int o0 = ob * 128;
    int cbase = ks * 320;

    int tid = threadIdx.x;
    int w8 = tid >> 6;                 // wave 0..7
    int wm = w8 >> 2;                  // t-half
    int wn = w8 & 3;                   // o-quarter
    int lane = tid & 63;
    int l31 = lane & 31;
    int lhi = lane >> 5;               // k-half within frag
    int rb = lane >> 3;                // staging: row-in-8
    int gsw = (lane & 7) ^ (rb & 7);   // pre-swizzled source granule

    v16f acc[2];
    #pragma unroll
    for (int mi = 0; mi < 2; mi++)
        #pragma unroll
        for (int e = 0; e < 16; e++) acc[mi][e] = 0.0f;

    const uint16_t* Abase = At + (size_t)(n * 128) * 3200 + gsw * 8;

    for (int kc = 0; kc < 5; kc++) {
        int c0 = cbase + kc * 64;
        // ---- stage A: 16 x 1KB chunks, chunk cid = i*8 + w8 ----
        #pragma unroll
        for (int i = 0; i < 2; i++) {
            int cid = i * 8 + w8;
            const uint16_t* src = Abase + (size_t)(cid * 8 + rb) * 3200 + c0;
            GLDS16(src, lds + cid * 1024);
        }
        // ---- stage B: 48 x 1KB chunks ----
        #pragma unroll
        for (int j = 0; j < 6; j++) {
            int cid = j * 8 + w8;
            int f0 = cid * 1024;
            int s = f0 >> 14;                    // split plane
            int r = ((f0 & 16383) >> 7) + rb;    // o-local row
            const uint16_t* src = Bs + (size_t)(s * 512 + o0 + r) * 3200
                                     + c0 + gsw * 8;
            GLDS16(src, lds + 16384 + f0);
        }
        __syncthreads();                         // drains vmcnt before barrier
        // ---- compute: 4 kf x (3 splits x 2 mi) MFMA per wave ----
        #pragma unroll
        for (int kf = 0; kf < 4; kf++) {
            int gc = kf * 2 + lhi;
            v8s av[2];
            #pragma unroll
            for (int mi = 0; mi < 2; mi++) {
                int t = wm * 64 + mi * 32 + l31;
                av[mi] = *(const v8s*)(lds + t * 128 + ((gc ^ (t & 7)) << 4));
            }
            #pragma unroll
            for (int s = 0; s < 3; s++) {
                int r = wn * 32 + l31;
                v8s bv = *(const v8s*)(lds + 16384 + s * 16384 + r * 128
                                       + ((gc ^ (r & 7)) << 4));
                #pragma unroll
                for (int mi = 0; mi < 2; mi++)
                    acc[mi] = __builtin_amdgcn_mfma_f32_32x32x16_bf16(
                        av[mi], bv, acc[mi], 0, 0, 0);
            }
        }
        __syncthreads();                         // LDS safe before next stage
    }
    // ---- epilogue: C/D layout col=lane&31, row=(r&3)+8*(r>>2)+4*(lane>>5) --
    float* yp = ypart + (size_t)ks * 1048576 + (size_t)n * 65536;
    int o = o0 + wn * 32 + l31;
    #pragma unroll
    for (int mi = 0; mi < 2; mi++) {
        #pragma unroll
        for (int r = 0; r < 16; r++) {
            int trow = wm * 64 + mi * 32 + (r & 3) + 8 * (r >> 2) + 4 * lhi;
            yp[trow * 512 + o] = acc[mi][r];
        }
    }
}

// ---------------- FC scan: fused 10-way reduce + LIF + delay (wide) ---------
// Block = 256 thr = 16 t x 16 o; 512 blocks = 16n x 32 o-groups.
// Phase A: all threads sum k=0..9 (ascending, same order as fc_reduce) for
// 16 rows x 128 t into LDS [16][132] (2-way-free). Phase B: 16 threads scan.
__global__ __launch_bounds__(256) void fc_scan(
    const float* __restrict__ yp,     // [10][16][128][512]
    float* __restrict__ out)          // [16][512][128]
{
    __shared__ float ldsX[16 * 132];  // 8,448 B
    int b = blockIdx.x;               // 512
    int n = b >> 5;
    int o0 = (b & 31) * 16;
    int tid = threadIdx.x;
    int t16 = tid >> 4, ol = tid & 15;
    const float* base = yp + (size_t)n * 65536 + o0 + ol;

    #pragma unroll
    for (int tb = 0; tb < 8; tb++) {
        int t = tb * 16 + t16;
        float x = base[(size_t)t * 512];
        #pragma unroll
        for (int k = 1; k < 10; k++)
            x += base[(size_t)k * 1048576 + (size_t)t * 512];
        ldsX[ol * 132 + t] = x;
    }
    __syncthreads();
    if (tid < 16) {
        int o = o0 + tid;
        const float* xr = &ldsX[tid * 132];
        float u = 0.f, v = 0.f;
        float prev = 0.f;             // final delay_shift
        float* op = out + ((size_t)(n * 512 + o)) * T;
        for (int tb = 0; tb < 32; tb++) {
            float bv[4];
            #pragma unroll
            for (int j = 0; j < 4; j++) {
                float s;
                neuron_step(xr[tb * 4 + j], u, v, s);
                bv[j] = prev; prev = s;
            }
            *(float4*)&op[tb * 4] = make_float4(bv[0], bv[1], bv[2], bv[3]);
        }
    }
}

// ---------------- launch ----------------------------------------------------
extern "C" void kernel_launch(void* const* d_in, const int* in_sizes, int n_in,
                              void* d_out, int out_size, void* d_ws, size_t ws_size,
                              hipStream_t stream) {
    const float* spike = (const float*)d_in[0];   // [16][2][40][40][128]
    const float* c1w   = (const float*)d_in[1];   // [8][2][3][3]
    const float* c2w   = (const float*)d_in[2];   // [16][8][3][3]
    const float* c3w   = (const float*)d_in[3];   // [32][16][3][3]
    const float* p1w   = (const float*)d_in[4];   // scalar
    const float* p2w   = (const float*)d_in[5];   // scalar
    const float* fcw   = (const float*)d_in[6];   // [512][3200]
    float* out = (float*)d_out;                   // [16][512][128]

    char* ws = (char*)d_ws;
    // Lifetime-ordered map (max 151,967,744):
    uint8_t*  s1    = (uint8_t*)(ws);             // -> 26,214,400
    uint16_t* Bs16  = (uint16_t*)(ws + 26214400); // -> 36,044,800 (alive->fc)
    uint16_t* Apk   = (uint16_t*)(ws + 36044800); // -> 36,100,096 (alive->conv3)
    uint16_t* s2P   = (uint16_t*)(ws + 36100096); // -> 67,819,520
    uint8_t*  s3    = (uint8_t*)(ws + 67819520);  // -> 80,926,720
    uint16_t* s4P   = (uint16_t*)(ws + 80926720); // -> 90,363,904
    uint8_t*  s5    = (uint8_t*)(ws + 90363904);  // -> 96,917,504
    uint16_t* At16  = (uint16_t*)(ws + 96917504); // -> 110,024,704
    float*    ypart = (float*)(ws + 110024704);   // -> 151,967,744

    prep<<<3662, 256, 0, stream>>>(fcw, c2w, c3w, Bs16, Apk, s2P, s4P);
    conv1_scan<<<3200, 256, 0, stream>>>(spike, c1w, s1);

    pool_pad<8, 20, 20><<<160, 320, 0, stream>>>(s1, p1w, s2P);
    conv_scan_mfma<16, 4, 20, 20><<<1600, 256, 0, stream>>>(s2P, Apk, 100.0f, s3);

    pool_pad<16, 10, 10><<<80, 320, 0, stream>>>(s3, p2w, s4P);
    conv_scan_mfma<32, 2, 10, 10><<<800, 256, 0, stream>>>(s4P, Apk + 13824, 100.0f, s5);

    sT_bf16<<<800, 256, 0, stream>>>(s5, At16);
    fc_gemm_mfma<<<640, 512, 0, stream>>>(At16, Bs16, ypart);
    fc_scan<<<512, 256, 0, stream>>>(ypart, out);
}

// Round 14
// 237.481 us; speedup vs baseline: 1.2793x; 1.0139x over previous
//
#include <hip/hip_runtime.h>
#include <stdint.h>

// SNN forward: prep -> conv1+scan(fused) -> pool1+pad(fused) -> conv2+scan
// (MFMA) -> pool2+pad(fused) -> conv3+scan(MFMA) -> sT -> fc(MFMA) ->
// fc_scan(fused 10-way reduce + LIF + delay, wide-parallel).
// Neuron: u=.75u+x; v=.96875v+u; s=(v>=100); v*=(1-s). Spikes u8 in d_ws.
// R9:  FC GEMM on matrix cores (exact 3-way bf16 weight split).
// R11: conv2/conv3 on matrix cores via pre-padded/delayed sP + A-frag weights.
// R12: scan fused INTO the MFMA convs; XCD-contiguous block swizzle.
// R13: conv1+scan fused; R14: XCD swizzles + pool_pad; R15: fc 8-wave + prep.
// R17: conv_scan_mfma PB halved -> 4 blocks/CU (confirmed 244us).
// R18/R19: conv1_scan restructures regressed -> R17 version kept.
// R20/R21: fc_reduce fused into fc_scan, then widened (512x256) -- 240.8us.
// R22: pool_pad re-blocked 320->64 threads (rows/block 320->64; pool1 CB=8,
// pool2 CB=4): old grids were 160/80 blocks -- 37%/69% of CUs completely
// idle on a ~58MB/15MB traffic kernel. New grids 800/400 spread the same
// rows chip-wide; per-row math, delay, scan order and sP writes are
// formula-identical -> bitwise-same outputs. Single-variable round.

#define T 128
#define AI 0.75f
#define AV 0.96875f
#define THETA 100.0f

typedef __attribute__((ext_vector_type(8))) short v8s;    // 8 x bf16 bits
typedef __attribute__((ext_vector_type(16))) float v16f;  // 32x32 acc

__device__ __forceinline__ void neuron_step(float x, float& u, float& v, float& s) {
    u = AI * u + x;
    v = AV * v + u;
    s = (v >= THETA) ? 1.0f : 0.0f;
    v = v * (1.0f - s);
}

// ---------------- conv1 + scan fused: spikes fp32 -> s1 u8 (R17 version) ----
// Block = (n, hy, 8-wx group); 256 thr = 8 wx x 32 t-threads.
__global__ __launch_bounds__(256) void conv1_scan(
    const float* __restrict__ in, const float* __restrict__ cw,
    uint8_t* __restrict__ sout)
{
    __shared__ float ldsF[64 * 130];             // 33,280 B
    int bid0 = blockIdx.x;                       // 3200 = 16n x 40hy x 5wg
    int bid = (bid0 & 7) * 400 + (bid0 >> 3);    // XCD-contiguous
    int wg = bid % 5;
    int hy = (bid / 5) % 40;
    int n  = bid / 200;
    int tid = threadIdx.x;
    int wxl = tid >> 5, tt = tid & 31, t0 = tt * 4;
    int wx = wg * 8 + wxl;

    float4 tap[18];
    #pragma unroll
    for (int c = 0; c < 2; c++)
      #pragma unroll
      for (int dh = 0; dh < 3; dh++)
        #pragma unroll
        for (int dw = 0; dw < 3; dw++) {
            int q = c * 9 + dh * 3 + dw;
            int hh = hy + dh - 1, ww = wx + dw - 1;
            bool ok = (hh >= 0) && (hh < 40) && (ww >= 0) && (ww < 40);
            tap[q] = ok ? *(const float4*)(in +
                (((size_t)(n * 2 + c) * 40 + hh) * 40 + ww) * T + t0)
                        : make_float4(0.f, 0.f, 0.f, 0.f);
        }

    #pragma unroll
    for (int o = 0; o < 8; o++) {
        const float* wp = cw + o * 18;           // uniform -> s_load
        float a0 = 0.f, a1 = 0.f, a2 = 0.f, a3 = 0.f;
        #pragma unroll
        for (int q = 0; q < 18; q++) {
            a0 += wp[q] * tap[q].x;  a1 += wp[q] * tap[q].y;
            a2 += wp[q] * tap[q].z;  a3 += wp[q] * tap[q].w;
        }
        float* xr = &ldsF[(o * 8 + wxl) * 130 + t0];
        xr[0] = a0 * 20.0f; xr[1] = a1 * 20.0f;
        xr[2] = a2 * 20.0f; xr[3] = a3 * 20.0f;
    }
    __syncthreads();
    if (tid < 64) {
        int o = tid >> 3, wxl2 = tid & 7;
        float u = 0.f, v = 0.f;
        uint32_t ob[32];
        const float* xr = &ldsF[tid * 130];
        #pragma unroll
        for (int tb = 0; tb < 32; tb++) {
            float s0, s1, s2, s3;
            neuron_step(xr[tb * 4 + 0], u, v, s0);
            neuron_step(xr[tb * 4 + 1], u, v, s1);
            neuron_step(xr[tb * 4 + 2], u, v, s2);
            neuron_step(xr[tb * 4 + 3], u, v, s3);
            ob[tb] = (uint32_t)s0 | ((uint32_t)s1 << 8) |
                     ((uint32_t)s2 << 16) | ((uint32_t)s3 << 24);
        }
        uint32_t* op = (uint32_t*)(sout +
            (((size_t)(n * 8 + o) * 40 + hy) * 40 + wg * 8 + wxl2) * T);
        #pragma unroll
        for (int k = 0; k < 8; k++)
            *(uint4*)&op[k * 4] =
                make_uint4(ob[k*4], ob[k*4+1], ob[k*4+2], ob[k*4+3]);
    }
}

// ---------------- pool_pad: 2x2 sum + scan + delay -> sP bf16 directly ------
// R22: 64-thread blocks, ROWS = C*CB = 64 rows/block. Per-row staging sums,
// byte-shift delay, scan order, sP writes formula-identical to the 320-thr
// version -- only the thread<->row mapping constants changed.
template<int C, int CB, int HO, int WO>
__global__ __launch_bounds__(64) void pool_pad(
    const uint8_t* __restrict__ in, const float* __restrict__ pw_ptr,
    uint16_t* __restrict__ sP)
{
    constexpr int ROWS = C * CB;                 // 64
    constexpr int GP = (HO * WO) / CB;           // cell-groups per n
    __shared__ uint8_t raw[ROWS * 132];          // 8,448 B, two overlaid uses
    uint32_t* ldsF = (uint32_t*)raw;             // [ROWS][20 u32] staging
    uint8_t*  sbuf = raw;                        // [ROWS][132 B] spikes

    int bid = blockIdx.x;                        // 16n x GP
    int grp = bid % GP, n = bid / GP;
    int tid = threadIdx.x;
    float pw = pw_ptr[0];

    float u = 0.f, v = 0.f;
    uint32_t ob[32];
    uint32_t carry = 0;

    #pragma unroll
    for (int tb = 0; tb < 2; tb++) {
        __syncthreads();
        #pragma unroll
        for (int k = 0; k < 4; k++) {
            int f = tid + k * 64;                // ROWS*4 quarter-rows
            int row = f >> 2, q = f & 3;
            int c = row / CB, p = row % CB;
            int hw = grp * CB + p;
            int wx = hw % WO, hy = hw / WO;
            const uint8_t* p00 = in +
                (((size_t)(n * C + c) * (2 * HO) + 2 * hy) * (2 * WO) + 2 * wx) * T;
            int off = tb * 64 + q * 16;
            uint4 a = *(const uint4*)(p00 + off);
            uint4 b = *(const uint4*)(p00 + T + off);
            uint4 cc = *(const uint4*)(p00 + 2 * WO * T + off);
            uint4 d = *(const uint4*)(p00 + 2 * WO * T + T + off);
            *(uint4*)&ldsF[row * 20 + q * 4] =
                make_uint4(a.x + b.x + cc.x + d.x, a.y + b.y + cc.y + d.y,
                           a.z + b.z + cc.z + d.z, a.w + b.w + cc.w + d.w);
        }
        __syncthreads();
        #pragma unroll
        for (int q = 0; q < 4; q++) {
            uint4 w = *(const uint4*)&ldsF[tid * 20 + q * 4];
            uint32_t words[4] = {w.x, w.y, w.z, w.w};
            #pragma unroll
            for (int j = 0; j < 4; j++) {
                uint32_t cur = words[j];
                uint32_t del = (cur << 8) | carry;   // delay_shift bytes
                carry = cur >> 24;
                float s0, s1, s2, s3;
                neuron_step(pw * (float)(del & 0xffu),         u, v, s0);
                neuron_step(pw * (float)((del >> 8) & 0xffu),  u, v, s1);
                neuron_step(pw * (float)((del >> 16) & 0xffu), u, v, s2);
                neuron_step(pw * (float)((del >> 24) & 0xffu), u, v, s3);
                ob[tb * 16 + q * 4 + j] = (uint32_t)s0 | ((uint32_t)s1 << 8) |
                                          ((uint32_t)s2 << 16) | ((uint32_t)s3 << 24);
            }
        }
    }

    // phase 3: spikes -> LDS byte rows (staging reads complete at barrier)
    __syncthreads();
    #pragma unroll
    for (int j = 0; j < 32; j++)
        *(uint32_t*)&sbuf[tid * 132 + j * 4] = ob[j];
    __syncthreads();

    // phase 4: transpose-write sP[cell][tau][16c], conv delay via tau-1
    constexpr int CHK = CB * 128;                // 32B chunks
    #pragma unroll
    for (int k = 0; k < CHK / 64; k++) {
        int ci = k * 64 + tid;
        int p = ci >> 7, tau = ci & 127;
        int hw = grp * CB + p;
        int wx = hw % WO, hy = hw / WO;
        uint32_t wb[8];
        #pragma unroll
        for (int e = 0; e < 16; e += 2) {
            uint32_t lo = 0u, hi = 0u;
            if (tau >= 1) {
                if (e < C)     lo = sbuf[(e * CB + p) * 132 + tau - 1] ? 0x3F80u : 0u;
                if (e + 1 < C) hi = sbuf[((e + 1) * CB + p) * 132 + tau - 1] ? 0x3F80u : 0u;
            }
            wb[e >> 1] = lo | (hi << 16);
        }
        uint16_t* dst = sP + ((size_t)((n * (HO + 2) + hy + 1) * (WO + 2)
                                       + wx + 1)) * 2048 + tau * 16;
        *(uint4*)dst       = make_uint4(wb[0], wb[1], wb[2], wb[3]);
        *(uint4*)(dst + 8) = make_uint4(wb[4], wb[5], wb[6], wb[7]);
    }
}

// ---------------- prep: wsplit + apack_w + halo zeroing, one dispatch -------
__global__ __launch_bounds__(256) void prep(
    const float* __restrict__ fw, const float* __restrict__ c2w,
    const float* __restrict__ c3w, uint16_t* __restrict__ bs,
    uint16_t* __restrict__ apk, uint16_t* __restrict__ s2P,
    uint16_t* __restrict__ s4P)
{
    int bid = blockIdx.x;
    int tid = threadIdx.x;
    if (bid < 1600) {
        int i = bid * 256 + tid;                 // 409,600 threads, 4 elems
        float4 wv = *(const float4*)(fw + i * 4);
        float w4[4] = {wv.x, wv.y, wv.z, wv.w};
        uint16_t h[4], m[4], l[4];
        #pragma unroll
        for (int j = 0; j < 4; j++) {
            uint32_t b0 = __float_as_uint(w4[j]);
            h[j] = (uint16_t)(b0 >> 16);
            float r1 = w4[j] - __uint_as_float(b0 & 0xFFFF0000u);   // exact
            uint32_t b1 = __float_as_uint(r1);
            m[j] = (uint16_t)(b1 >> 16);
            float r2 = r1 - __uint_as_float(b1 & 0xFFFF0000u);      // exact
            l[j] = (uint16_t)(__float_as_uint(r2) >> 16);           // exact
        }
        *(ushort4*)(bs +       0 + i * 4) = make_ushort4(h[0], h[1], h[2], h[3]);
        *(ushort4*)(bs + 1638400 + i * 4) = make_ushort4(m[0], m[1], m[2], m[3]);
        *(ushort4*)(bs + 3276800 + i * 4) = make_ushort4(l[0], l[1], l[2], l[3]);
    } else if (bid < 1614) {
        int unit = (bid - 1600) * 4 + (tid >> 6);    // 0..55, 54 used
        if (unit >= 54) return;
        int conv = unit / 27;
        int plane = (unit % 27) / 9;
        int dlt = unit % 9;
        int lane = tid & 63;
        int o = lane & 31, chi = (lane >> 5) * 8;
        int CO = conv ? 32 : 16;
        int CI = conv ? 16 : 8;
        const float* Wp = conv ? c3w : c2w;
        uint32_t wb[4] = {0u, 0u, 0u, 0u};
        #pragma unroll
        for (int e = 0; e < 8; e++) {
            int c = chi + e;
            float w = (o < CO && c < CI) ? Wp[((size_t)o * CI + c) * 9 + dlt] : 0.f;
            uint32_t b0 = __float_as_uint(w);
            uint16_t hi = (uint16_t)(b0 >> 16);
            float r1 = w - __uint_as_float(b0 & 0xFFFF0000u);     // exact
            uint32_t b1 = __float_as_uint(r1);
            uint16_t md = (uint16_t)(b1 >> 16);
            float r2 = r1 - __uint_as_float(b1 & 0xFFFF0000u);    // exact
            uint16_t lo = (uint16_t)(__float_as_uint(r2) >> 16);  // exact
            uint32_t pv = (plane == 0) ? hi : ((plane == 1) ? md : lo);
            wb[e >> 1] |= pv << ((e & 1) * 16);
        }
        *(uint4*)(apk + ((size_t)conv * 27 + plane * 9 + dlt) * 512 + lane * 8) =
            make_uint4(wb[0], wb[1], wb[2], wb[3]);
    } else {
        int hid = bid - 1614;
        uint8_t* dst;
        if (hid < 1344) {                        // conv2 ring: 16n x 84
            int n = hid / 84, r = hid % 84;
            int hy, wx;
            if (r < 22)      { hy = 0;  wx = r; }
            else if (r < 44) { hy = 21; wx = r - 22; }
            else { int r2 = r - 44; hy = 1 + (r2 >> 1); wx = (r2 & 1) ? 21 : 0; }
            dst = (uint8_t*)s2P + ((size_t)(n * 484) + hy * 22 + wx) * 4096;
        } else {                                 // conv3 ring: 16n x 44
            int h2 = hid - 1344;
            int n = h2 / 44, r = h2 % 44;
            int hy, wx;
            if (r < 12)      { hy = 0;  wx = r; }
            else if (r < 24) { hy = 11; wx = r - 12; }
            else { int r2 = r - 24; hy = 1 + (r2 >> 1); wx = (r2 & 1) ? 11 : 0; }
            dst = (uint8_t*)s4P + ((size_t)(n * 144) + hy * 12 + wx) * 4096;
        }
        *(uint4*)(dst + tid * 16) = make_uint4(0u, 0u, 0u, 0u);
    }
}

// ---------------- conv_scan_mfma: MFMA conv + in-block LIF scan -------------
// Block = 256 thr (4 waves = 4 tau-chunks) x PB positions, all COUT, all T.
// R17: PB halved -> LDS 33,280 B -> 4 blocks/CU, 4 waves/SIMD.
template<int COUT, int PB, int H, int W>
__global__ __launch_bounds__(256, 2) void conv_scan_mfma(
    const uint16_t* __restrict__ sP, const uint16_t* __restrict__ apk,
    float scale, uint8_t* __restrict__ sout)
{
    constexpr int ROWS = COUT * PB;              // 64
    __shared__ float ldsF[ROWS * 130];           // 33,280 B
    constexpr int HW = H * W;
    constexpr int GP = HW / PB;
    int per = (16 * GP) >> 3;                    // blocks per XCD
    int vbid = (blockIdx.x & 7) * per + (blockIdx.x >> 3);
    int n = vbid / GP, grp = vbid % GP;
    int tid = threadIdx.x;
    int wv = tid >> 6, lane = tid & 63;
    int l31 = lane & 31, lhi = lane >> 5;
    int t0 = wv * 32;

    const uint16_t* ap = apk + (size_t)lane * 8;
    v8s a0[9], a1[9], a2[9];
    #pragma unroll
    for (int d = 0; d < 9; d++) {
        a0[d] = *(const v8s*)(ap + d * 512);
        a1[d] = *(const v8s*)(ap + (9 + d) * 512);
        a2[d] = *(const v8s*)(ap + (18 + d) * 512);
    }

    #pragma unroll
    for (int p = 0; p < PB; p++) {
        int hw = grp * PB + p;
        int hy = hw / W, wx = hw % W;
        v8s bfr[9];
        #pragma unroll
        for (int d = 0; d < 9; d++) {
            int dh = d / 3, dw = d % 3;
            const uint16_t* src = sP
                + ((size_t)((n * (H + 2) + hy + dh) * (W + 2) + wx + dw)) * 2048
                + (t0 + l31) * 16 + lhi * 8;
            bfr[d] = *(const v8s*)src;
        }
        v16f ac0, ac1, ac2;
        #pragma unroll
        for (int e = 0; e < 16; e++) { ac0[e] = 0.f; ac1[e] = 0.f; ac2[e] = 0.f; }
        #pragma unroll
        for (int d = 0; d < 9; d++) {
            ac0 = __builtin_amdgcn_mfma_f32_32x32x16_bf16(a0[d], bfr[d], ac0, 0, 0, 0);
            ac1 = __builtin_amdgcn_mfma_f32_32x32x16_bf16(a1[d], bfr[d], ac1, 0, 0, 0);
            ac2 = __builtin_amdgcn_mfma_f32_32x32x16_bf16(a2[d], bfr[d], ac2, 0, 0, 0);
        }
        constexpr int NR = (COUT == 32) ? 16 : 8;
        #pragma unroll
        for (int r = 0; r < NR; r++) {
            int o = (r & 3) + 8 * (r >> 2) + 4 * lhi;
            ldsF[(o * PB + p) * 130 + t0 + l31] =
                (ac0[r] + ac1[r] + ac2[r]) * scale;
        }
    }
    __syncthreads();
    if (tid < ROWS) {
        int o = tid / PB, p = tid % PB;
        int hw = grp * PB + p;
        float u = 0.f, v = 0.f;
        uint32_t ob[32];
        const float* xr = &ldsF[tid * 130];
        #pragma unroll
        for (int tb = 0; tb < 32; tb++) {
            float2 xa = *(const float2*)(xr + tb * 4);
            float2 xb = *(const float2*)(xr + tb * 4 + 2);
            float s0, s1, s2, s3;
            neuron_step(xa.x, u, v, s0); neuron_step(xa.y, u, v, s1);
            neuron_step(xb.x, u, v, s2); neuron_step(xb.y, u, v, s3);
            ob[tb] = (uint32_t)s0 | ((uint32_t)s1 << 8) |
                     ((uint32_t)s2 << 16) | ((uint32_t)s3 << 24);
        }
        uint32_t* op = (uint32_t*)(sout + ((size_t)(n * COUT + o) * HW + hw) * 128);
        #pragma unroll
        for (int k = 0; k < 8; k++)
            *(uint4*)&op[k * 4] =
                make_uint4(ob[k*4], ob[k*4+1], ob[k*4+2], ob[k*4+3]);
    }
}

// ---------------- sT: s5 u8 [16][3200][128] -> At bf16 [16][128][3200] ------
__global__ __launch_bounds__(256) void sT_bf16(
    const uint8_t* __restrict__ s5, uint16_t* __restrict__ At)
{
    __shared__ uint8_t tile[64 * 132];           // 64 c-rows x 128 t (+4 pad)
    int bid = blockIdx.x;                        // 800 = 16 n x 50 chunks
    int n = bid / 50;
    int c0 = (bid % 50) * 64;
    int tid = threadIdx.x;
    {
        int row = tid >> 2, q = tid & 3;
        const uint8_t* src = s5 + ((size_t)(n * 3200 + c0 + row)) * T + q * 32;
        *(uint4*)&tile[row * 132 + q * 32]      = *(const uint4*)src;
        *(uint4*)&tile[row * 132 + q * 32 + 16] = *(const uint4*)(src + 16);
    }
    __syncthreads();
    int t = tid >> 1, half = tid & 1;
    uint32_t wb[16];
    if (t == 0) {
        #pragma unroll
        for (int j = 0; j < 16; j++) wb[j] = 0u;
    } else {
        #pragma unroll
        for (int j = 0; j < 16; j++) {
            uint32_t lo = tile[(half * 32 + 2 * j) * 132 + (t - 1)] ? 0x3F80u : 0u;
            uint32_t hi = tile[(half * 32 + 2 * j + 1) * 132 + (t - 1)] ? 0x3F80u : 0u;
            wb[j] = lo | (hi << 16);
        }
    }
    uint16_t* dst = At + ((size_t)(n * 128 + t)) * 3200 + c0 + half * 32;
    #pragma unroll
    for (int k = 0; k < 4; k++)
        *(uint4*)(dst + k * 8) = make_uint4(wb[k*4], wb[k*4+1], wb[k*4+2], wb[k*4+3]);
}

// ---------------- FC GEMM on matrix cores (8 waves, 2x4 split) --------------
#define GLDS16(g, s) __builtin_amdgcn_global_load_lds( \
    (const __attribute__((address_space(1))) uint32_t*)(g), \
    (__attribute__((address_space(3))) uint32_t*)(s), 16, 0, 0)

__global__ __launch_bounds__(512, 4) void fc_gemm_mfma(
    const uint16_t* __restrict__ At,   // [16][128][3200] bf16
    const uint16_t* __restrict__ Bs,   // [3][512][3200] bf16
    float* __restrict__ ypart)         // [10][16][128][512] f32
{
    __shared__ uint8_t lds[65536];     // A [128][64]bf16 @0; B 3x[128][64] @16K
    int bid0 = blockIdx.x;             // 640 = 10ks x 4ob x 16n (n fastest)
    int bid = (bid0 & 7) * 80 + (bid0 >> 3);     // XCD-contiguous
    int n  = bid & 15;
    int ob = (bid >> 4) & 3;
    int ks = bid >> 6;
    int o0 = ob * 128;
    int cbase = ks * 320;

    int tid = threadIdx.x;
    int w8 = tid >> 6;                 // wave 0..7
    int wm = w8 >> 2;                  // t-half
    int wn = w8 & 3;                   // o-quarter
    int lane = tid & 63;
    int l31 = lane & 31;
    int lhi = lane >> 5;               // k-half within frag
    int rb = lane >> 3;                // staging: row-in-8
    int gsw = (lane & 7) ^ (rb & 7);   // pre-swizzled source granule

    v16f acc[2];
    #pragma unroll
    for (int mi = 0; mi < 2; mi++)
        #pragma unroll
        for (int e = 0; e < 16; e++) acc[mi][e] = 0.0f;

    const uint16_t* Abase = At + (size_t)(n * 128) * 3200 + gsw * 8;

    for (int kc = 0; kc < 5; kc++) {
        int c0 = cbase + kc * 64;
        // ---- stage A: 16 x 1KB chunks, chunk cid = i*8 + w8 ----
        #pragma unroll
        for (int i = 0; i < 2; i++) {
            int cid = i * 8 + w8;
            const uint16_t* src = Abase + (size_t)(cid * 8 + rb) * 3200 + c0;
            GLDS16(src, lds + cid * 1024);
        }
        // ---- stage B: 48 x 1KB chunks ----
        #pragma unroll
        for (int j = 0; j < 6; j++) {
            int cid = j * 8 + w8;
            int f0 = cid * 1024;
            int s = f0 >> 14;                    // split plane
            int r = ((f0 & 16383) >> 7) + rb;    // o-local row
            const uint16_t* src = Bs + (size_t)(s * 512 + o0 + r) * 3200
                                     + c0 + gsw * 8;
            GLDS16(src, lds + 16384 + f0);
        }
        __syncthreads();                         // drains vmcnt before barrier
        // ---- compute: 4 kf x (3 splits x 2 mi) MFMA per wave ----
        #pragma unroll
        for (int kf = 0; kf < 4; kf++) {
            int gc = kf * 2 + lhi;
            v8s av[2];
            #pragma unroll
            for (int mi = 0; mi < 2; mi++) {
                int t = wm * 64 + mi * 32 + l31;
                av[mi] = *(const v8s*)(lds + t * 128 + ((gc ^ (t & 7)) << 4));
            }
            #pragma unroll
            for (int s = 0; s < 3; s++) {
                int r = wn * 32 + l31;
                v8s bv = *(const v8s*)(lds + 16384 + s * 16384 + r * 128
                                       + ((gc ^ (r & 7)) << 4));
                #pragma unroll
                for (int mi = 0; mi < 2; mi++)
                    acc[mi] = __builtin_amdgcn_mfma_f32_32x32x16_bf16(
                        av[mi], bv, acc[mi], 0, 0, 0);
            }
        }
        __syncthreads();                         // LDS safe before next stage
    }
    // ---- epilogue: C/D layout col=lane&31, row=(r&3)+8*(r>>2)+4*(lane>>5) --
    float* yp = ypart + (size_t)ks * 1048576 + (size_t)n * 65536;
    int o = o0 + wn * 32 + l31;
    #pragma unroll
    for (int mi = 0; mi < 2; mi++) {
        #pragma unroll
        for (int r = 0; r < 16; r++) {
            int trow = wm * 64 + mi * 32 + (r & 3) + 8 * (r >> 2) + 4 * lhi;
            yp[trow * 512 + o] = acc[mi][r];
        }
    }
}

// ---------------- FC scan: fused 10-way reduce + LIF + delay (wide) ---------
// Block = 256 thr = 16 t x 16 o; 512 blocks = 16n x 32 o-groups.
__global__ __launch_bounds__(256) void fc_scan(
    const float* __restrict__ yp,     // [10][16][128][512]
    float* __restrict__ out)          // [16][512][128]
{
    __shared__ float ldsX[16 * 132];  // 8,448 B
    int b = blockIdx.x;               // 512
    int n = b >> 5;
    int o0 = (b & 31) * 16;
    int tid = threadIdx.x;
    int t16 = tid >> 4, ol = tid & 15;
    const float* base = yp + (size_t)n * 65536 + o0 + ol;

    #pragma unroll
    for (int tb = 0; tb < 8; tb++) {
        int t = tb * 16 + t16;
        float x = base[(size_t)t * 512];
        #pragma unroll
        for (int k = 1; k < 10; k++)
            x += base[(size_t)k * 1048576 + (size_t)t * 512];
        ldsX[ol * 132 + t] = x;
    }
    __syncthreads();
    if (tid < 16) {
        int o = o0 + tid;
        const float* xr = &ldsX[tid * 132];
        float u = 0.f, v = 0.f;
        float prev = 0.f;             // final delay_shift
        float* op = out + ((size_t)(n * 512 + o)) * T;
        for (int tb = 0; tb < 32; tb++) {
            float bv[4];
            #pragma unroll
            for (int j = 0; j < 4; j++) {
                float s;
                neuron_step(xr[tb * 4 + j], u, v, s);
                bv[j] = prev; prev = s;
            }
            *(float4*)&op[tb * 4] = make_float4(bv[0], bv[1], bv[2], bv[3]);
        }
    }
}

// ---------------- launch ----------------------------------------------------
extern "C" void kernel_launch(void* const* d_in, const int* in_sizes, int n_in,
                              void* d_out, int out_size, void* d_ws, size_t ws_size,
                              hipStream_t stream) {
    const float* spike = (const float*)d_in[0];   // [16][2][40][40][128]
    const float* c1w   = (const float*)d_in[1];   // [8][2][3][3]
    const float* c2w   = (const float*)d_in[2];   // [16][8][3][3]
    const float* c3w   = (const float*)d_in[3];   // [32][16][3][3]
    const float* p1w   = (const float*)d_in[4];   // scalar
    const float* p2w   = (const float*)d_in[5];   // scalar
    const float* fcw   = (const float*)d_in[6];   // [512][3200]
    float* out = (float*)d_out;                   // [16][512][128]

    char* ws = (char*)d_ws;
    // Lifetime-ordered map (max 151,967,744):
    uint8_t*  s1    = (uint8_t*)(ws);             // -> 26,214,400
    uint16_t* Bs16  = (uint16_t*)(ws + 26214400); // -> 36,044,800 (alive->fc)
    uint16_t* Apk   = (uint16_t*)(ws + 36044800); // -> 36,100,096 (alive->conv3)
    uint16_t* s2P   = (uint16_t*)(ws + 36100096); // -> 67,819,520
    uint8_t*  s3    = (uint8_t*)(ws + 67819520);  // -> 80,926,720
    uint16_t* s4P   = (uint16_t*)(ws + 80926720); // -> 90,363,904
    uint8_t*  s5    = (uint8_t*)(ws + 90363904);  // -> 96,917,504
    uint16_t* At16  = (uint16_t*)(ws + 96917504); // -> 110,024,704
    float*    ypart = (float*)(ws + 110024704);   // -> 151,967,744

    prep<<<3662, 256, 0, stream>>>(fcw, c2w, c3w, Bs16, Apk, s2P, s4P);
    conv1_scan<<<3200, 256, 0, stream>>>(spike, c1w, s1);

    pool_pad<8, 8, 20, 20><<<800, 64, 0, stream>>>(s1, p1w, s2P);
    conv_scan_mfma<16, 4, 20, 20><<<1600, 256, 0, stream>>>(s2P, Apk, 100.0f, s3);

    pool_pad<16, 4, 10, 10><<<400, 64, 0, stream>>>(s3, p2w, s4P);
    conv_scan_mfma<32, 2, 10, 10><<<800, 256, 0, stream>>>(s4P, Apk + 13824, 100.0f, s5);

    sT_bf16<<<800, 256, 0, stream>>>(s5, At16);
    fc_gemm_mfma<<<640, 512, 0, stream>>>(At16, Bs16, ypart);
    fc_scan<<<512, 256, 0, stream>>>(ypart, out);
}

// Round 15
// 231.243 us; speedup vs baseline: 1.3138x; 1.0270x over previous
//
#include <hip/hip_runtime.h>
#include <stdint.h>

// SNN forward: [prep||conv1+scan](merged) -> pool1+pad(fused) -> conv2+scan
// (MFMA) -> pool2+pad(fused) -> conv3+scan(MFMA) -> sT -> fc(MFMA) ->
// fc_scan(fused 10-way reduce + LIF + delay, wide-parallel).
// Neuron: u=.75u+x; v=.96875v+u; s=(v>=100); v*=(1-s). Spikes u8 in d_ws.
// R9:  FC GEMM on matrix cores (exact 3-way bf16 weight split).
// R11: conv2/conv3 on matrix cores via pre-padded/delayed sP + A-frag weights.
// R12: scan fused INTO the MFMA convs; XCD-contiguous block swizzle.
// R13: conv1+scan fused; R14: XCD swizzles + pool_pad; R15: fc 8-wave + prep.
// R17: conv_scan_mfma PB halved -> 4 blocks/CU (confirmed 244us).
// R18/R19: conv1_scan restructures regressed -> R17 version kept (its
// local optimum is sharp; VALU floor ~24us vs ~35 measured, left alone).
// R20/R21: fc_reduce fused into fc_scan, widened (512x256) -- 240.8us.
// R22: pool_pad re-blocked to 64-thr/800+400 blocks -- 237.5us.
// R23: prep merged INTO the conv1_scan dispatch (blocks 0..3199 = conv1
// with its swizzle untouched; 3200..6861 = prep with pbid=bid-3200):
// prep has zero data dependence on conv1 but was stream-serialized before
// it. Removes one launch gap; prep's ~16MB of memory work overlaps conv1's
// VALU-heavy blocks. Per-block-uniform branch, byte-identical math.

#define T 128
#define AI 0.75f
#define AV 0.96875f
#define THETA 100.0f

typedef __attribute__((ext_vector_type(8))) short v8s;    // 8 x bf16 bits
typedef __attribute__((ext_vector_type(16))) float v16f;  // 32x32 acc

__device__ __forceinline__ void neuron_step(float x, float& u, float& v, float& s) {
    u = AI * u + x;
    v = AV * v + u;
    s = (v >= THETA) ? 1.0f : 0.0f;
    v = v * (1.0f - s);
}

// ---------------- conv1+scan (blocks 0..3199) || prep (3200..6861) ----------
// conv1 path: block = (n, hy, 8-wx group); 256 thr = 8 wx x 32 t-threads.
// Phase 1: x[o][wx][t] -> LDS (FMA order identical to old conv1_x).
// Phase 2: 64 threads scan one (o,wx) row each over t, write u8 spikes.
// prep path: wsplit (pbid<1600), apack_w (<1614), halo ring zeroing (rest).
__global__ __launch_bounds__(256) void conv1_prep(
    const float* __restrict__ in, const float* __restrict__ cw,
    uint8_t* __restrict__ sout,
    const float* __restrict__ fw, const float* __restrict__ c2w,
    const float* __restrict__ c3w, uint16_t* __restrict__ bs,
    uint16_t* __restrict__ apk, uint16_t* __restrict__ s2P,
    uint16_t* __restrict__ s4P)
{
    __shared__ float ldsF[64 * 130];             // 33,280 B (conv1 path only)
    int tid = threadIdx.x;

    if (blockIdx.x >= 3200) {                    // ---- prep path ----
        int pbid = blockIdx.x - 3200;            // 0..3661
        if (pbid < 1600) {
            int i = pbid * 256 + tid;            // 409,600 threads, 4 elems
            float4 wv = *(const float4*)(fw + i * 4);
            float w4[4] = {wv.x, wv.y, wv.z, wv.w};
            uint16_t h[4], m[4], l[4];
            #pragma unroll
            for (int j = 0; j < 4; j++) {
                uint32_t b0 = __float_as_uint(w4[j]);
                h[j] = (uint16_t)(b0 >> 16);
                float r1 = w4[j] - __uint_as_float(b0 & 0xFFFF0000u);   // exact
                uint32_t b1 = __float_as_uint(r1);
                m[j] = (uint16_t)(b1 >> 16);
                float r2 = r1 - __uint_as_float(b1 & 0xFFFF0000u);      // exact
                l[j] = (uint16_t)(__float_as_uint(r2) >> 16);           // exact
            }
            *(ushort4*)(bs +       0 + i * 4) = make_ushort4(h[0], h[1], h[2], h[3]);
            *(ushort4*)(bs + 1638400 + i * 4) = make_ushort4(m[0], m[1], m[2], m[3]);
            *(ushort4*)(bs + 3276800 + i * 4) = make_ushort4(l[0], l[1], l[2], l[3]);
        } else if (pbid < 1614) {
            int unit = (pbid - 1600) * 4 + (tid >> 6);   // 0..55, 54 used
            if (unit >= 54) return;
            int conv = unit / 27;
            int plane = (unit % 27) / 9;
            int dlt = unit % 9;
            int lane = tid & 63;
            int o = lane & 31, chi = (lane >> 5) * 8;
            int CO = conv ? 32 : 16;
            int CI = conv ? 16 : 8;
            const float* Wp = conv ? c3w : c2w;
            uint32_t wb[4] = {0u, 0u, 0u, 0u};
            #pragma unroll
            for (int e = 0; e < 8; e++) {
                int c = chi + e;
                float w = (o < CO && c < CI) ? Wp[((size_t)o * CI + c) * 9 + dlt] : 0.f;
                uint32_t b0 = __float_as_uint(w);
                uint16_t hi = (uint16_t)(b0 >> 16);
                float r1 = w - __uint_as_float(b0 & 0xFFFF0000u);     // exact
                uint32_t b1 = __float_as_uint(r1);
                uint16_t md = (uint16_t)(b1 >> 16);
                float r2 = r1 - __uint_as_float(b1 & 0xFFFF0000u);    // exact
                uint16_t lo = (uint16_t)(__float_as_uint(r2) >> 16);  // exact
                uint32_t pv = (plane == 0) ? hi : ((plane == 1) ? md : lo);
                wb[e >> 1] |= pv << ((e & 1) * 16);
            }
            *(uint4*)(apk + ((size_t)conv * 27 + plane * 9 + dlt) * 512 + lane * 8) =
                make_uint4(wb[0], wb[1], wb[2], wb[3]);
        } else {
            int hid = pbid - 1614;
            uint8_t* dst;
            if (hid < 1344) {                    // conv2 ring: 16n x 84
                int n = hid / 84, r = hid % 84;
                int hy, wx;
                if (r < 22)      { hy = 0;  wx = r; }
                else if (r < 44) { hy = 21; wx = r - 22; }
                else { int r2 = r - 44; hy = 1 + (r2 >> 1); wx = (r2 & 1) ? 21 : 0; }
                dst = (uint8_t*)s2P + ((size_t)(n * 484) + hy * 22 + wx) * 4096;
            } else {                             // conv3 ring: 16n x 44
                int h2 = hid - 1344;
                int n = h2 / 44, r = h2 % 44;
                int hy, wx;
                if (r < 12)      { hy = 0;  wx = r; }
                else if (r < 24) { hy = 11; wx = r - 12; }
                else { int r2 = r - 24; hy = 1 + (r2 >> 1); wx = (r2 & 1) ? 11 : 0; }
                dst = (uint8_t*)s4P + ((size_t)(n * 144) + hy * 12 + wx) * 4096;
            }
            *(uint4*)(dst + tid * 16) = make_uint4(0u, 0u, 0u, 0u);
        }
        return;
    }

    // ---- conv1 path (identical to R17 conv1_scan) ----
    int bid0 = blockIdx.x;                       // 3200 = 16n x 40hy x 5wg
    int bid = (bid0 & 7) * 400 + (bid0 >> 3);    // XCD-contiguous
    int wg = bid % 5;
    int hy = (bid / 5) % 40;
    int n  = bid / 200;
    int wxl = tid >> 5, tt = tid & 31, t0 = tt * 4;
    int wx = wg * 8 + wxl;

    float4 tap[18];
    #pragma unroll
    for (int c = 0; c < 2; c++)
      #pragma unroll
      for (int dh = 0; dh < 3; dh++)
        #pragma unroll
        for (int dw = 0; dw < 3; dw++) {
            int q = c * 9 + dh * 3 + dw;
            int hh = hy + dh - 1, ww = wx + dw - 1;
            bool ok = (hh >= 0) && (hh < 40) && (ww >= 0) && (ww < 40);
            tap[q] = ok ? *(const float4*)(in +
                (((size_t)(n * 2 + c) * 40 + hh) * 40 + ww) * T + t0)
                        : make_float4(0.f, 0.f, 0.f, 0.f);
        }

    #pragma unroll
    for (int o = 0; o < 8; o++) {
        const float* wp = cw + o * 18;           // uniform -> s_load
        float a0 = 0.f, a1 = 0.f, a2 = 0.f, a3 = 0.f;
        #pragma unroll
        for (int q = 0; q < 18; q++) {
            a0 += wp[q] * tap[q].x;  a1 += wp[q] * tap[q].y;
            a2 += wp[q] * tap[q].z;  a3 += wp[q] * tap[q].w;
        }
        float* xr = &ldsF[(o * 8 + wxl) * 130 + t0];
        xr[0] = a0 * 20.0f; xr[1] = a1 * 20.0f;
        xr[2] = a2 * 20.0f; xr[3] = a3 * 20.0f;
    }
    __syncthreads();
    if (tid < 64) {
        int o = tid >> 3, wxl2 = tid & 7;
        float u = 0.f, v = 0.f;
        uint32_t ob[32];
        const float* xr = &ldsF[tid * 130];
        #pragma unroll
        for (int tb = 0; tb < 32; tb++) {
            float s0, s1, s2, s3;
            neuron_step(xr[tb * 4 + 0], u, v, s0);
            neuron_step(xr[tb * 4 + 1], u, v, s1);
            neuron_step(xr[tb * 4 + 2], u, v, s2);
            neuron_step(xr[tb * 4 + 3], u, v, s3);
            ob[tb] = (uint32_t)s0 | ((uint32_t)s1 << 8) |
                     ((uint32_t)s2 << 16) | ((uint32_t)s3 << 24);
        }
        uint32_t* op = (uint32_t*)(sout +
            (((size_t)(n * 8 + o) * 40 + hy) * 40 + wg * 8 + wxl2) * T);
        #pragma unroll
        for (int k = 0; k < 8; k++)
            *(uint4*)&op[k * 4] =
                make_uint4(ob[k*4], ob[k*4+1], ob[k*4+2], ob[k*4+3]);
    }
}

// ---------------- pool_pad: 2x2 sum + scan + delay -> sP bf16 directly ------
// R22: 64-thread blocks, ROWS = C*CB = 64 rows/block.
template<int C, int CB, int HO, int WO>
__global__ __launch_bounds__(64) void pool_pad(
    const uint8_t* __restrict__ in, const float* __restrict__ pw_ptr,
    uint16_t* __restrict__ sP)
{
    constexpr int ROWS = C * CB;                 // 64
    constexpr int GP = (HO * WO) / CB;           // cell-groups per n
    __shared__ uint8_t raw[ROWS * 132];          // 8,448 B, two overlaid uses
    uint32_t* ldsF = (uint32_t*)raw;             // [ROWS][20 u32] staging
    uint8_t*  sbuf = raw;                        // [ROWS][132 B] spikes

    int bid = blockIdx.x;                        // 16n x GP
    int grp = bid % GP, n = bid / GP;
    int tid = threadIdx.x;
    float pw = pw_ptr[0];

    float u = 0.f, v = 0.f;
    uint32_t ob[32];
    uint32_t carry = 0;

    #pragma unroll
    for (int tb = 0; tb < 2; tb++) {
        __syncthreads();
        #pragma unroll
        for (int k = 0; k < 4; k++) {
            int f = tid + k * 64;                // ROWS*4 quarter-rows
            int row = f >> 2, q = f & 3;
            int c = row / CB, p = row % CB;
            int hw = grp * CB + p;
            int wx = hw % WO, hy = hw / WO;
            const uint8_t* p00 = in +
                (((size_t)(n * C + c) * (2 * HO) + 2 * hy) * (2 * WO) + 2 * wx) * T;
            int off = tb * 64 + q * 16;
            uint4 a = *(const uint4*)(p00 + off);
            uint4 b = *(const uint4*)(p00 + T + off);
            uint4 cc = *(const uint4*)(p00 + 2 * WO * T + off);
            uint4 d = *(const uint4*)(p00 + 2 * WO * T + T + off);
            *(uint4*)&ldsF[row * 20 + q * 4] =
                make_uint4(a.x + b.x + cc.x + d.x, a.y + b.y + cc.y + d.y,
                           a.z + b.z + cc.z + d.z, a.w + b.w + cc.w + d.w);
        }
        __syncthreads();
        #pragma unroll
        for (int q = 0; q < 4; q++) {
            uint4 w = *(const uint4*)&ldsF[tid * 20 + q * 4];
            uint32_t words[4] = {w.x, w.y, w.z, w.w};
            #pragma unroll
            for (int j = 0; j < 4; j++) {
                uint32_t cur = words[j];
                uint32_t del = (cur << 8) | carry;   // delay_shift bytes
                carry = cur >> 24;
                float s0, s1, s2, s3;
                neuron_step(pw * (float)(del & 0xffu),         u, v, s0);
                neuron_step(pw * (float)((del >> 8) & 0xffu),  u, v, s1);
                neuron_step(pw * (float)((del >> 16) & 0xffu), u, v, s2);
                neuron_step(pw * (float)((del >> 24) & 0xffu), u, v, s3);
                ob[tb * 16 + q * 4 + j] = (uint32_t)s0 | ((uint32_t)s1 << 8) |
                                          ((uint32_t)s2 << 16) | ((uint32_t)s3 << 24);
            }
        }
    }

    // phase 3: spikes -> LDS byte rows (staging reads complete at barrier)
    __syncthreads();
    #pragma unroll
    for (int j = 0; j < 32; j++)
        *(uint32_t*)&sbuf[tid * 132 + j * 4] = ob[j];
    __syncthreads();

    // phase 4: transpose-write sP[cell][tau][16c], conv delay via tau-1
    constexpr int CHK = CB * 128;                // 32B chunks
    #pragma unroll
    for (int k = 0; k < CHK / 64; k++) {
        int ci = k * 64 + tid;
        int p = ci >> 7, tau = ci & 127;
        int hw = grp * CB + p;
        int wx = hw % WO, hy = hw / WO;
        uint32_t wb[8];
        #pragma unroll
        for (int e = 0; e < 16; e += 2) {
            uint32_t lo = 0u, hi = 0u;
            if (tau >= 1) {
                if (e < C)     lo = sbuf[(e * CB + p) * 132 + tau - 1] ? 0x3F80u : 0u;
                if (e + 1 < C) hi = sbuf[((e + 1) * CB + p) * 132 + tau - 1] ? 0x3F80u : 0u;
            }
            wb[e >> 1] = lo | (hi << 16);
        }
        uint16_t* dst = sP + ((size_t)((n * (HO + 2) + hy + 1) * (WO + 2)
                                       + wx + 1)) * 2048 + tau * 16;
        *(uint4*)dst       = make_uint4(wb[0], wb[1], wb[2], wb[3]);
        *(uint4*)(dst + 8) = make_uint4(wb[4], wb[5], wb[6], wb[7]);
    }
}

// ---------------- conv_scan_mfma: MFMA conv + in-block LIF scan -------------
// Block = 256 thr (4 waves = 4 tau-chunks) x PB positions, all COUT, all T.
// R17: PB halved -> LDS 33,280 B -> 4 blocks/CU, 4 waves/SIMD.
template<int COUT, int PB, int H, int W>
__global__ __launch_bounds__(256, 2) void conv_scan_mfma(
    const uint16_t* __restrict__ sP, const uint16_t* __restrict__ apk,
    float scale, uint8_t* __restrict__ sout)
{
    constexpr int ROWS = COUT * PB;              // 64
    __shared__ float ldsF[ROWS * 130];           // 33,280 B
    constexpr int HW = H * W;
    constexpr int GP = HW / PB;
    int per = (16 * GP) >> 3;                    // blocks per XCD
    int vbid = (blockIdx.x & 7) * per + (blockIdx.x >> 3);
    int n = vbid / GP, grp = vbid % GP;
    int tid = threadIdx.x;
    int wv = tid >> 6, lane = tid & 63;
    int l31 = lane & 31, lhi = lane >> 5;
    int t0 = wv * 32;

    const uint16_t* ap = apk + (size_t)lane * 8;
    v8s a0[9], a1[9], a2[9];
    #pragma unroll
    for (int d = 0; d < 9; d++) {
        a0[d] = *(const v8s*)(ap + d * 512);
        a1[d] = *(const v8s*)(ap + (9 + d) * 512);
        a2[d] = *(const v8s*)(ap + (18 + d) * 512);
    }

    #pragma unroll
    for (int p = 0; p < PB; p++) {
        int hw = grp * PB + p;
        int hy = hw / W, wx = hw % W;
        v8s bfr[9];
        #pragma unroll
        for (int d = 0; d < 9; d++) {
            int dh = d / 3, dw = d % 3;
            const uint16_t* src = sP
                + ((size_t)((n * (H + 2) + hy + dh) * (W + 2) + wx + dw)) * 2048
                + (t0 + l31) * 16 + lhi * 8;
            bfr[d] = *(const v8s*)src;
        }
        v16f ac0, ac1, ac2;
        #pragma unroll
        for (int e = 0; e < 16; e++) { ac0[e] = 0.f; ac1[e] = 0.f; ac2[e] = 0.f; }
        #pragma unroll
        for (int d = 0; d < 9; d++) {
            ac0 = __builtin_amdgcn_mfma_f32_32x32x16_bf16(a0[d], bfr[d], ac0, 0, 0, 0);
            ac1 = __builtin_amdgcn_mfma_f32_32x32x16_bf16(a1[d], bfr[d], ac1, 0, 0, 0);
            ac2 = __builtin_amdgcn_mfma_f32_32x32x16_bf16(a2[d], bfr[d], ac2, 0, 0, 0);
        }
        constexpr int NR = (COUT == 32) ? 16 : 8;
        #pragma unroll
        for (int r = 0; r < NR; r++) {
            int o = (r & 3) + 8 * (r >> 2) + 4 * lhi;
            ldsF[(o * PB + p) * 130 + t0 + l31] =
                (ac0[r] + ac1[r] + ac2[r]) * scale;
        }
    }
    __syncthreads();
    if (tid < ROWS) {
        int o = tid / PB, p = tid % PB;
        int hw = grp * PB + p;
        float u = 0.f, v = 0.f;
        uint32_t ob[32];
        const float* xr = &ldsF[tid * 130];
        #pragma unroll
        for (int tb = 0; tb < 32; tb++) {
            float2 xa = *(const float2*)(xr + tb * 4);
            float2 xb = *(const float2*)(xr + tb * 4 + 2);
            float s0, s1, s2, s3;
            neuron_step(xa.x, u, v, s0); neuron_step(xa.y, u, v, s1);
            neuron_step(xb.x, u, v, s2); neuron_step(xb.y, u, v, s3);
            ob[tb] = (uint32_t)s0 | ((uint32_t)s1 << 8) |
                     ((uint32_t)s2 << 16) | ((uint32_t)s3 << 24);
        }
        uint32_t* op = (uint32_t*)(sout + ((size_t)(n * COUT + o) * HW + hw) * 128);
        #pragma unroll
        for (int k = 0; k < 8; k++)
            *(uint4*)&op[k * 4] =
                make_uint4(ob[k*4], ob[k*4+1], ob[k*4+2], ob[k*4+3]);
    }
}

// ---------------- sT: s5 u8 [16][3200][128] -> At bf16 [16][128][3200] ------
__global__ __launch_bounds__(256) void sT_bf16(
    const uint8_t* __restrict__ s5, uint16_t* __restrict__ At)
{
    __shared__ uint8_t tile[64 * 132];           // 64 c-rows x 128 t (+4 pad)
    int bid = blockIdx.x;                        // 800 = 16 n x 50 chunks
    int n = bid / 50;
    int c0 = (bid % 50) * 64;
    int tid = threadIdx.x;
    {
        int row = tid >> 2, q = tid & 3;
        const uint8_t* src = s5 + ((size_t)(n * 3200 + c0 + row)) * T + q * 32;
        *(uint4*)&tile[row * 132 + q * 32]      = *(const uint4*)src;
        *(uint4*)&tile[row * 132 + q * 32 + 16] = *(const uint4*)(src + 16);
    }
    __syncthreads();
    int t = tid >> 1, half = tid & 1;
    uint32_t wb[16];
    if (t == 0) {
        #pragma unroll
        for (int j = 0; j < 16; j++) wb[j] = 0u;
    } else {
        #pragma unroll
        for (int j = 0; j < 16; j++) {
            uint32_t lo = tile[(half * 32 + 2 * j) * 132 + (t - 1)] ? 0x3F80u : 0u;
            uint32_t hi = tile[(half * 32 + 2 * j + 1) * 132 + (t - 1)] ? 0x3F80u : 0u;
            wb[j] = lo | (hi << 16);
        }
    }
    uint16_t* dst = At + ((size_t)(n * 128 + t)) * 3200 + c0 + half * 32;
    #pragma unroll
    for (int k = 0; k < 4; k++)
        *(uint4*)(dst + k * 8) = make_uint4(wb[k*4], wb[k*4+1], wb[k*4+2], wb[k*4+3]);
}

// ---------------- FC GEMM on matrix cores (8 waves, 2x4 split) --------------
#define GLDS16(g, s) __builtin_amdgcn_global_load_lds( \
    (const __attribute__((address_space(1))) uint32_t*)(g), \
    (__attribute__((address_space(3))) uint32_t*)(s), 16, 0, 0)

__global__ __launch_bounds__(512, 4) void fc_gemm_mfma(
    const uint16_t* __restrict__ At,   // [16][128][3200] bf16
    const uint16_t* __restrict__ Bs,   // [3][512][3200] bf16
    float* __restrict__ ypart)         // [10][16][128][512] f32
{
    __shared__ uint8_t lds[65536];     // A [128][64]bf16 @0; B 3x[128][64] @16K
    int bid0 = blockIdx.x;             // 640 = 10ks x 4ob x 16n (n fastest)
    int bid = (bid0 & 7) * 80 + (bid0 >> 3);     // XCD-contiguous
    int n  = bid & 15;
    int ob = (bid >> 4) & 3;
    int ks = bid >> 6;
    int o0 = ob * 128;
    int cbase = ks * 320;

    int tid = threadIdx.x;
    int w8 = tid >> 6;                 // wave 0..7
    int wm = w8 >> 2;                  // t-half
    int wn = w8 & 3;                   // o-quarter
    int lane = tid & 63;
    int l31 = lane & 31;
    int lhi = lane >> 5;               // k-half within frag
    int rb = lane >> 3;                // staging: row-in-8
    int gsw = (lane & 7) ^ (rb & 7);   // pre-swizzled source granule

    v16f acc[2];
    #pragma unroll
    for (int mi = 0; mi < 2; mi++)
        #pragma unroll
        for (int e = 0; e < 16; e++) acc[mi][e] = 0.0f;

    const uint16_t* Abase = At + (size_t)(n * 128) * 3200 + gsw * 8;

    for (int kc = 0; kc < 5; kc++) {
        int c0 = cbase + kc * 64;
        // ---- stage A: 16 x 1KB chunks, chunk cid = i*8 + w8 ----
        #pragma unroll
        for (int i = 0; i < 2; i++) {
            int cid = i * 8 + w8;
            const uint16_t* src = Abase + (size_t)(cid * 8 + rb) * 3200 + c0;
            GLDS16(src, lds + cid * 1024);
        }
        // ---- stage B: 48 x 1KB chunks ----
        #pragma unroll
        for (int j = 0; j < 6; j++) {
            int cid = j * 8 + w8;
            int f0 = cid * 1024;
            int s = f0 >> 14;                    // split plane
            int r = ((f0 & 16383) >> 7) + rb;    // o-local row
            const uint16_t* src = Bs + (size_t)(s * 512 + o0 + r) * 3200
                                     + c0 + gsw * 8;
            GLDS16(src, lds + 16384 + f0);
        }
        __syncthreads();                         // drains vmcnt before barrier
        // ---- compute: 4 kf x (3 splits x 2 mi) MFMA per wave ----
        #pragma unroll
        for (int kf = 0; kf < 4; kf++) {
            int gc = kf * 2 + lhi;
            v8s av[2];
            #pragma unroll
            for (int mi = 0; mi < 2; mi++) {
                int t = wm * 64 + mi * 32 + l31;
                av[mi] = *(const v8s*)(lds + t * 128 + ((gc ^ (t & 7)) << 4));
            }
            #pragma unroll
            for (int s = 0; s < 3; s++) {
                int r = wn * 32 + l31;
                v8s bv = *(const v8s*)(lds + 16384 + s * 16384 + r * 128
                                       + ((gc ^ (r & 7)) << 4));
                #pragma unroll
                for (int mi = 0; mi < 2; mi++)
                    acc[mi] = __builtin_amdgcn_mfma_f32_32x32x16_bf16(
                        av[mi], bv, acc[mi], 0, 0, 0);
            }
        }
        __syncthreads();                         // LDS safe before next stage
    }
    // ---- epilogue: C/D layout col=lane&31, row=(r&3)+8*(r>>2)+4*(lane>>5) --
    float* yp = ypart + (size_t)ks * 1048576 + (size_t)n * 65536;
    int o = o0 + wn * 32 + l31;
    #pragma unroll
    for (int mi = 0; mi < 2; mi++) {
        #pragma unroll
        for (int r = 0; r < 16; r++) {
            int trow = wm * 64 + mi * 32 + (r & 3) + 8 * (r >> 2) + 4 * lhi;
            yp[trow * 512 + o] = acc[mi][r];
        }
    }
}

// ---------------- FC scan: fused 10-way reduce + LIF + delay (wide) ---------
// Block = 256 thr = 16 t x 16 o; 512 blocks = 16n x 32 o-groups.
__global__ __launch_bounds__(256) void fc_scan(
    const float* __restrict__ yp,     // [10][16][128][512]
    float* __restrict__ out)          // [16][512][128]
{
    __shared__ float ldsX[16 * 132];  // 8,448 B
    int b = blockIdx.x;               // 512
    int n = b >> 5;
    int o0 = (b & 31) * 16;
    int tid = threadIdx.x;
    int t16 = tid >> 4, ol = tid & 15;
    const float* base = yp + (size_t)n * 65536 + o0 + ol;

    #pragma unroll
    for (int tb = 0; tb < 8; tb++) {
        int t = tb * 16 + t16;
        float x = base[(size_t)t * 512];
        #pragma unroll
        for (int k = 1; k < 10; k++)
            x += base[(size_t)k * 1048576 + (size_t)t * 512];
        ldsX[ol * 132 + t] = x;
    }
    __syncthreads();
    if (tid < 16) {
        int o = o0 + tid;
        const float* xr = &ldsX[tid * 132];
        float u = 0.f, v = 0.f;
        float prev = 0.f;             // final delay_shift
        float* op = out + ((size_t)(n * 512 + o)) * T;
        for (int tb = 0; tb < 32; tb++) {
            float bv[4];
            #pragma unroll
            for (int j = 0; j < 4; j++) {
                float s;
                neuron_step(xr[tb * 4 + j], u, v, s);
                bv[j] = prev; prev = s;
            }
            *(float4*)&op[tb * 4] = make_float4(bv[0], bv[1], bv[2], bv[3]);
        }
    }
}

// ---------------- launch ----------------------------------------------------
extern "C" void kernel_launch(void* const* d_in, const int* in_sizes, int n_in,
                              void* d_out, int out_size, void* d_ws, size_t ws_size,
                              hipStream_t stream) {
    const float* spike = (const float*)d_in[0];   // [16][2][40][40][128]
    const float* c1w   = (const float*)d_in[1];   // [8][2][3][3]
    const float* c2w   = (const float*)d_in[2];   // [16][8][3][3]
    const float* c3w   = (const float*)d_in[3];   // [32][16][3][3]
    const float* p1w   = (const float*)d_in[4];   // scalar
    const float* p2w   = (const float*)d_in[5];   // scalar
    const float* fcw   = (const float*)d_in[6];   // [512][3200]
    float* out = (float*)d_out;                   // [16][512][128]

    char* ws = (char*)d_ws;
    // Lifetime-ordered map (max 151,967,744):
    uint8_t*  s1    = (uint8_t*)(ws);             // -> 26,214,400
    uint16_t* Bs16  = (uint16_t*)(ws + 26214400); // -> 36,044,800 (alive->fc)
    uint16_t* Apk   = (uint16_t*)(ws + 36044800); // -> 36,100,096 (alive->conv3)
    uint16_t* s2P   = (uint16_t*)(ws + 36100096); // -> 67,819,520
    uint8_t*  s3    = (uint8_t*)(ws + 67819520);  // -> 80,926,720
    uint16_t* s4P   = (uint16_t*)(ws + 80926720); // -> 90,363,904
    uint8_t*  s5    = (uint8_t*)(ws + 90363904);  // -> 96,917,504
    uint16_t* At16  = (uint16_t*)(ws + 96917504); // -> 110,024,704
    float*    ypart = (float*)(ws + 110024704);   // -> 151,967,744

    conv1_prep<<<6862, 256, 0, stream>>>(spike, c1w, s1,
                                         fcw, c2w, c3w, Bs16, Apk, s2P, s4P);

    pool_pad<8, 8, 20, 20><<<800, 64, 0, stream>>>(s1, p1w, s2P);
    conv_scan_mfma<16, 4, 20, 20><<<1600, 256, 0, stream>>>(s2P, Apk, 100.0f, s3);

    pool_pad<16, 4, 10, 10><<<400, 64, 0, stream>>>(s3, p2w, s4P);
    conv_scan_mfma<32, 2, 10, 10><<<800, 256, 0, stream>>>(s4P, Apk + 13824, 100.0f, s5);

    sT_bf16<<<800, 256, 0, stream>>>(s5, At16);
    fc_gemm_mfma<<<640, 512, 0, stream>>>(At16, Bs16, ypart);
    fc_scan<<<512, 256, 0, stream>>>(ypart, out);
}

// Round 16
// 230.043 us; speedup vs baseline: 1.3206x; 1.0052x over previous
//
#include <hip/hip_runtime.h>
#include <stdint.h>

// SNN forward: [prep||conv1+scan](merged) -> pool1+pad(fused) -> conv2+scan
// (MFMA) -> pool2+pad(fused) -> conv3+scan+At-transpose(MFMA, fused) ->
// fc(MFMA) -> fc_scan(fused 10-way reduce + LIF + delay, wide-parallel).
// Neuron: u=.75u+x; v=.96875v+u; s=(v>=100); v*=(1-s). Spikes u8 in d_ws.
// R9:  FC GEMM on matrix cores (exact 3-way bf16 weight split).
// R11: conv2/conv3 on matrix cores via pre-padded/delayed sP + A-frag weights.
// R12: scan fused INTO the MFMA convs; XCD-contiguous block swizzle.
// R13: conv1+scan fused; R14: XCD swizzles + pool_pad; R15: fc 8-wave + prep.
// R17: conv_scan_mfma PB halved -> 4 blocks/CU (confirmed 244us).
// R18/R19: conv1_scan restructures regressed -> R17 version kept.
// R20/R21: fc_reduce fused into fc_scan, widened -- 240.8us.
// R22: pool_pad 64-thr blocks -- 237.5us. R23: prep||conv1 merged -- 231.2us.
// R24: s5/sT bounce deleted. FC K-dim permuted c' = hw*32 + o (bijection):
// a conv3 block (n,grp) then owns the contiguous c' window [64*grp,64*grp+64),
// so conv3_scan_at stages its spikes to LDS and runs sT's transpose body
// verbatim (c0=grp*64) writing At directly. prep's wsplit writes Bs in the
// same permuted order (gathered fcw reads, hidden under conv1). fc_gemm is
// byte-identical (both operands consistently permuted; only FP32 sum order
// shifts -- same reordering class as the validated MFMA conversions).
// Deletes the sT dispatch, s5 buffer, ~13MB HBM traffic.

#define T 128
#define AI 0.75f
#define AV 0.96875f
#define THETA 100.0f

typedef __attribute__((ext_vector_type(8))) short v8s;    // 8 x bf16 bits
typedef __attribute__((ext_vector_type(16))) float v16f;  // 32x32 acc

__device__ __forceinline__ void neuron_step(float x, float& u, float& v, float& s) {
    u = AI * u + x;
    v = AV * v + u;
    s = (v >= THETA) ? 1.0f : 0.0f;
    v = v * (1.0f - s);
}

// ---------------- conv1+scan (blocks 0..3199) || prep (3200..6861) ----------
__global__ __launch_bounds__(256) void conv1_prep(
    const float* __restrict__ in, const float* __restrict__ cw,
    uint8_t* __restrict__ sout,
    const float* __restrict__ fw, const float* __restrict__ c2w,
    const float* __restrict__ c3w, uint16_t* __restrict__ bs,
    uint16_t* __restrict__ apk, uint16_t* __restrict__ s2P,
    uint16_t* __restrict__ s4P)
{
    __shared__ float ldsF[64 * 130];             // 33,280 B (conv1 path only)
    int tid = threadIdx.x;

    if (blockIdx.x >= 3200) {                    // ---- prep path ----
        int pbid = blockIdx.x - 3200;            // 0..3661
        if (pbid < 1600) {
            // wsplit with K-permutation: Bs[s][o][c'] = split(fcw[o][orig_c]),
            // orig_c = (c'&31)*100 + (c'>>5)  (c' = hw*32 + o_c bijection)
            int i4 = (pbid * 256 + tid) * 4;     // 4 consecutive (o,c') flats
            uint16_t h[4], m[4], l[4];
            #pragma unroll
            for (int j = 0; j < 4; j++) {
                int flat = i4 + j;
                int o = flat / 3200;
                int cp = flat - o * 3200;
                int orig = o * 3200 + (cp & 31) * 100 + (cp >> 5);
                float w = fw[orig];
                uint32_t b0 = __float_as_uint(w);
                h[j] = (uint16_t)(b0 >> 16);
                float r1 = w - __uint_as_float(b0 & 0xFFFF0000u);   // exact
                uint32_t b1 = __float_as_uint(r1);
                m[j] = (uint16_t)(b1 >> 16);
                float r2 = r1 - __uint_as_float(b1 & 0xFFFF0000u);  // exact
                l[j] = (uint16_t)(__float_as_uint(r2) >> 16);       // exact
            }
            *(ushort4*)(bs +       0 + i4) = make_ushort4(h[0], h[1], h[2], h[3]);
            *(ushort4*)(bs + 1638400 + i4) = make_ushort4(m[0], m[1], m[2], m[3]);
            *(ushort4*)(bs + 3276800 + i4) = make_ushort4(l[0], l[1], l[2], l[3]);
        } else if (pbid < 1614) {
            int unit = (pbid - 1600) * 4 + (tid >> 6);   // 0..55, 54 used
            if (unit >= 54) return;
            int conv = unit / 27;
            int plane = (unit % 27) / 9;
            int dlt = unit % 9;
            int lane = tid & 63;
            int o = lane & 31, chi = (lane >> 5) * 8;
            int CO = conv ? 32 : 16;
            int CI = conv ? 16 : 8;
            const float* Wp = conv ? c3w : c2w;
            uint32_t wb[4] = {0u, 0u, 0u, 0u};
            #pragma unroll
            for (int e = 0; e < 8; e++) {
                int c = chi + e;
                float w = (o < CO && c < CI) ? Wp[((size_t)o * CI + c) * 9 + dlt] : 0.f;
                uint32_t b0 = __float_as_uint(w);
                uint16_t hi = (uint16_t)(b0 >> 16);
                float r1 = w - __uint_as_float(b0 & 0xFFFF0000u);     // exact
                uint32_t b1 = __float_as_uint(r1);
                uint16_t md = (uint16_t)(b1 >> 16);
                float r2 = r1 - __uint_as_float(b1 & 0xFFFF0000u);    // exact
                uint16_t lo = (uint16_t)(__float_as_uint(r2) >> 16);  // exact
                uint32_t pv = (plane == 0) ? hi : ((plane == 1) ? md : lo);
                wb[e >> 1] |= pv << ((e & 1) * 16);
            }
            *(uint4*)(apk + ((size_t)conv * 27 + plane * 9 + dlt) * 512 + lane * 8) =
                make_uint4(wb[0], wb[1], wb[2], wb[3]);
        } else {
            int hid = pbid - 1614;
            uint8_t* dst;
            if (hid < 1344) {                    // conv2 ring: 16n x 84
                int n = hid / 84, r = hid % 84;
                int hy, wx;
                if (r < 22)      { hy = 0;  wx = r; }
                else if (r < 44) { hy = 21; wx = r - 22; }
                else { int r2 = r - 44; hy = 1 + (r2 >> 1); wx = (r2 & 1) ? 21 : 0; }
                dst = (uint8_t*)s2P + ((size_t)(n * 484) + hy * 22 + wx) * 4096;
            } else {                             // conv3 ring: 16n x 44
                int h2 = hid - 1344;
                int n = h2 / 44, r = h2 % 44;
                int hy, wx;
                if (r < 12)      { hy = 0;  wx = r; }
                else if (r < 24) { hy = 11; wx = r - 12; }
                else { int r2 = r - 24; hy = 1 + (r2 >> 1); wx = (r2 & 1) ? 11 : 0; }
                dst = (uint8_t*)s4P + ((size_t)(n * 144) + hy * 12 + wx) * 4096;
            }
            *(uint4*)(dst + tid * 16) = make_uint4(0u, 0u, 0u, 0u);
        }
        return;
    }

    // ---- conv1 path (identical to R17 conv1_scan) ----
    int bid0 = blockIdx.x;                       // 3200 = 16n x 40hy x 5wg
    int bid = (bid0 & 7) * 400 + (bid0 >> 3);    // XCD-contiguous
    int wg = bid % 5;
    int hy = (bid / 5) % 40;
    int n  = bid / 200;
    int wxl = tid >> 5, tt = tid & 31, t0 = tt * 4;
    int wx = wg * 8 + wxl;

    float4 tap[18];
    #pragma unroll
    for (int c = 0; c < 2; c++)
      #pragma unroll
      for (int dh = 0; dh < 3; dh++)
        #pragma unroll
        for (int dw = 0; dw < 3; dw++) {
            int q = c * 9 + dh * 3 + dw;
            int hh = hy + dh - 1, ww = wx + dw - 1;
            bool ok = (hh >= 0) && (hh < 40) && (ww >= 0) && (ww < 40);
            tap[q] = ok ? *(const float4*)(in +
                (((size_t)(n * 2 + c) * 40 + hh) * 40 + ww) * T + t0)
                        : make_float4(0.f, 0.f, 0.f, 0.f);
        }

    #pragma unroll
    for (int o = 0; o < 8; o++) {
        const float* wp = cw + o * 18;           // uniform -> s_load
        float a0 = 0.f, a1 = 0.f, a2 = 0.f, a3 = 0.f;
        #pragma unroll
        for (int q = 0; q < 18; q++) {
            a0 += wp[q] * tap[q].x;  a1 += wp[q] * tap[q].y;
            a2 += wp[q] * tap[q].z;  a3 += wp[q] * tap[q].w;
        }
        float* xr = &ldsF[(o * 8 + wxl) * 130 + t0];
        xr[0] = a0 * 20.0f; xr[1] = a1 * 20.0f;
        xr[2] = a2 * 20.0f; xr[3] = a3 * 20.0f;
    }
    __syncthreads();
    if (tid < 64) {
        int o = tid >> 3, wxl2 = tid & 7;
        float u = 0.f, v = 0.f;
        uint32_t ob[32];
        const float* xr = &ldsF[tid * 130];
        #pragma unroll
        for (int tb = 0; tb < 32; tb++) {
            float s0, s1, s2, s3;
            neuron_step(xr[tb * 4 + 0], u, v, s0);
            neuron_step(xr[tb * 4 + 1], u, v, s1);
            neuron_step(xr[tb * 4 + 2], u, v, s2);
            neuron_step(xr[tb * 4 + 3], u, v, s3);
            ob[tb] = (uint32_t)s0 | ((uint32_t)s1 << 8) |
                     ((uint32_t)s2 << 16) | ((uint32_t)s3 << 24);
        }
        uint32_t* op = (uint32_t*)(sout +
            (((size_t)(n * 8 + o) * 40 + hy) * 40 + wg * 8 + wxl2) * T);
        #pragma unroll
        for (int k = 0; k < 8; k++)
            *(uint4*)&op[k * 4] =
                make_uint4(ob[k*4], ob[k*4+1], ob[k*4+2], ob[k*4+3]);
    }
}

// ---------------- pool_pad: 2x2 sum + scan + delay -> sP bf16 directly ------
// R22: 64-thread blocks, ROWS = C*CB = 64 rows/block.
template<int C, int CB, int HO, int WO>
__global__ __launch_bounds__(64) void pool_pad(
    const uint8_t* __restrict__ in, const float* __restrict__ pw_ptr,
    uint16_t* __restrict__ sP)
{
    constexpr int ROWS = C * CB;                 // 64
    constexpr int GP = (HO * WO) / CB;           // cell-groups per n
    __shared__ uint8_t raw[ROWS * 132];          // 8,448 B, two overlaid uses
    uint32_t* ldsF = (uint32_t*)raw;             // [ROWS][20 u32] staging
    uint8_t*  sbuf = raw;                        // [ROWS][132 B] spikes

    int bid = blockIdx.x;                        // 16n x GP
    int grp = bid % GP, n = bid / GP;
    int tid = threadIdx.x;
    float pw = pw_ptr[0];

    float u = 0.f, v = 0.f;
    uint32_t ob[32];
    uint32_t carry = 0;

    #pragma unroll
    for (int tb = 0; tb < 2; tb++) {
        __syncthreads();
        #pragma unroll
        for (int k = 0; k < 4; k++) {
            int f = tid + k * 64;                // ROWS*4 quarter-rows
            int row = f >> 2, q = f & 3;
            int c = row / CB, p = row % CB;
            int hw = grp * CB + p;
            int wx = hw % WO, hy = hw / WO;
            const uint8_t* p00 = in +
                (((size_t)(n * C + c) * (2 * HO) + 2 * hy) * (2 * WO) + 2 * wx) * T;
            int off = tb * 64 + q * 16;
            uint4 a = *(const uint4*)(p00 + off);
            uint4 b = *(const uint4*)(p00 + T + off);
            uint4 cc = *(const uint4*)(p00 + 2 * WO * T + off);
            uint4 d = *(const uint4*)(p00 + 2 * WO * T + T + off);
            *(uint4*)&ldsF[row * 20 + q * 4] =
                make_uint4(a.x + b.x + cc.x + d.x, a.y + b.y + cc.y + d.y,
                           a.z + b.z + cc.z + d.z, a.w + b.w + cc.w + d.w);
        }
        __syncthreads();
        #pragma unroll
        for (int q = 0; q < 4; q++) {
            uint4 w = *(const uint4*)&ldsF[tid * 20 + q * 4];
            uint32_t words[4] = {w.x, w.y, w.z, w.w};
            #pragma unroll
            for (int j = 0; j < 4; j++) {
                uint32_t cur = words[j];
                uint32_t del = (cur << 8) | carry;   // delay_shift bytes
                carry = cur >> 24;
                float s0, s1, s2, s3;
                neuron_step(pw * (float)(del & 0xffu),         u, v, s0);
                neuron_step(pw * (float)((del >> 8) & 0xffu),  u, v, s1);
                neuron_step(pw * (float)((del >> 16) & 0xffu), u, v, s2);
                neuron_step(pw * (float)((del >> 24) & 0xffu), u, v, s3);
                ob[tb * 16 + q * 4 + j] = (uint32_t)s0 | ((uint32_t)s1 << 8) |
                                          ((uint32_t)s2 << 16) | ((uint32_t)s3 << 24);
            }
        }
    }

    // phase 3: spikes -> LDS byte rows (staging reads complete at barrier)
    __syncthreads();
    #pragma unroll
    for (int j = 0; j < 32; j++)
        *(uint32_t*)&sbuf[tid * 132 + j * 4] = ob[j];
    __syncthreads();

    // phase 4: transpose-write sP[cell][tau][16c], conv delay via tau-1
    constexpr int CHK = CB * 128;                // 32B chunks
    #pragma unroll
    for (int k = 0; k < CHK / 64; k++) {
        int ci = k * 64 + tid;
        int p = ci >> 7, tau = ci & 127;
        int hw = grp * CB + p;
        int wx = hw % WO, hy = hw / WO;
        uint32_t wb[8];
        #pragma unroll
        for (int e = 0; e < 16; e += 2) {
            uint32_t lo = 0u, hi = 0u;
            if (tau >= 1) {
                if (e < C)     lo = sbuf[(e * CB + p) * 132 + tau - 1] ? 0x3F80u : 0u;
                if (e + 1 < C) hi = sbuf[((e + 1) * CB + p) * 132 + tau - 1] ? 0x3F80u : 0u;
            }
            wb[e >> 1] = lo | (hi << 16);
        }
        uint16_t* dst = sP + ((size_t)((n * (HO + 2) + hy + 1) * (WO + 2)
                                       + wx + 1)) * 2048 + tau * 16;
        *(uint4*)dst       = make_uint4(wb[0], wb[1], wb[2], wb[3]);
        *(uint4*)(dst + 8) = make_uint4(wb[4], wb[5], wb[6], wb[7]);
    }
}

// ---------------- conv_scan_mfma: MFMA conv + in-block LIF scan (conv2) -----
template<int COUT, int PB, int H, int W>
__global__ __launch_bounds__(256, 2) void conv_scan_mfma(
    const uint16_t* __restrict__ sP, const uint16_t* __restrict__ apk,
    float scale, uint8_t* __restrict__ sout)
{
    constexpr int ROWS = COUT * PB;              // 64
    __shared__ float ldsF[ROWS * 130];           // 33,280 B
    constexpr int HW = H * W;
    constexpr int GP = HW / PB;
    int per = (16 * GP) >> 3;                    // blocks per XCD
    int vbid = (blockIdx.x & 7) * per + (blockIdx.x >> 3);
    int n = vbid / GP, grp = vbid % GP;
    int tid = threadIdx.x;
    int wv = tid >> 6, lane = tid & 63;
    int l31 = lane & 31, lhi = lane >> 5;
    int t0 = wv * 32;

    const uint16_t* ap = apk + (size_t)lane * 8;
    v8s a0[9], a1[9], a2[9];
    #pragma unroll
    for (int d = 0; d < 9; d++) {
        a0[d] = *(const v8s*)(ap + d * 512);
        a1[d] = *(const v8s*)(ap + (9 + d) * 512);
        a2[d] = *(const v8s*)(ap + (18 + d) * 512);
    }

    #pragma unroll
    for (int p = 0; p < PB; p++) {
        int hw = grp * PB + p;
        int hy = hw / W, wx = hw % W;
        v8s bfr[9];
        #pragma unroll
        for (int d = 0; d < 9; d++) {
            int dh = d / 3, dw = d % 3;
            const uint16_t* src = sP
                + ((size_t)((n * (H + 2) + hy + dh) * (W + 2) + wx + dw)) * 2048
                + (t0 + l31) * 16 + lhi * 8;
            bfr[d] = *(const v8s*)src;
        }
        v16f ac0, ac1, ac2;
        #pragma unroll
        for (int e = 0; e < 16; e++) { ac0[e] = 0.f; ac1[e] = 0.f; ac2[e] = 0.f; }
        #pragma unroll
        for (int d = 0; d < 9; d++) {
            ac0 = __builtin_amdgcn_mfma_f32_32x32x16_bf16(a0[d], bfr[d], ac0, 0, 0, 0);
            ac1 = __builtin_amdgcn_mfma_f32_32x32x16_bf16(a1[d], bfr[d], ac1, 0, 0, 0);
            ac2 = __builtin_amdgcn_mfma_f32_32x32x16_bf16(a2[d], bfr[d], ac2, 0, 0, 0);
        }
        constexpr int NR = (COUT == 32) ? 16 : 8;
        #pragma unroll
        for (int r = 0; r < NR; r++) {
            int o = (r & 3) + 8 * (r >> 2) + 4 * lhi;
            ldsF[(o * PB + p) * 130 + t0 + l31] =
                (ac0[r] + ac1[r] + ac2[r]) * scale;
        }
    }
    __syncthreads();
    if (tid < ROWS) {
        int o = tid / PB, p = tid % PB;
        int hw = grp * PB + p;
        float u = 0.f, v = 0.f;
        uint32_t ob[32];
        const float* xr = &ldsF[tid * 130];
        #pragma unroll
        for (int tb = 0; tb < 32; tb++) {
            float2 xa = *(const float2*)(xr + tb * 4);
            float2 xb = *(const float2*)(xr + tb * 4 + 2);
            float s0, s1, s2, s3;
            neuron_step(xa.x, u, v, s0); neuron_step(xa.y, u, v, s1);
            neuron_step(xb.x, u, v, s2); neuron_step(xb.y, u, v, s3);
            ob[tb] = (uint32_t)s0 | ((uint32_t)s1 << 8) |
                     ((uint32_t)s2 << 16) | ((uint32_t)s3 << 24);
        }
        uint32_t* op = (uint32_t*)(sout + ((size_t)(n * COUT + o) * HW + hw) * 128);
        #pragma unroll
        for (int k = 0; k < 8; k++)
            *(uint4*)&op[k * 4] =
                make_uint4(ob[k*4], ob[k*4+1], ob[k*4+2], ob[k*4+3]);
    }
}

// ---------------- conv3_scan_at: conv3 MFMA + scan + At transpose -----------
// Same phases 1-2 as conv_scan_mfma<32,2,10,10>, but spikes go to LDS
// (row = p*32 + o = c'-local, c' = hw*32 + o) and a 3rd phase runs the old
// sT transpose body with c0 = grp*64, writing At[n][t][c'] = spike[t-1].
__global__ __launch_bounds__(256, 2) void conv3_scan_at(
    const uint16_t* __restrict__ sP, const uint16_t* __restrict__ apk,
    float scale, uint16_t* __restrict__ At)
{
    __shared__ float ldsF[64 * 130];             // 33,280 B
    __shared__ uint8_t sbuf[64 * 132];           //  8,448 B (total 41,728)
    constexpr int W = 10, HW = 100, PB = 2, GP = 50;
    int per = (16 * GP) >> 3;                    // 100 blocks per XCD
    int vbid = (blockIdx.x & 7) * per + (blockIdx.x >> 3);
    int n = vbid / GP, grp = vbid % GP;
    int tid = threadIdx.x;
    int wv = tid >> 6, lane = tid & 63;
    int l31 = lane & 31, lhi = lane >> 5;
    int t0 = wv * 32;

    const uint16_t* ap = apk + (size_t)lane * 8;
    v8s a0[9], a1[9], a2[9];
    #pragma unroll
    for (int d = 0; d < 9; d++) {
        a0[d] = *(const v8s*)(ap + d * 512);
        a1[d] = *(const v8s*)(ap + (9 + d) * 512);
        a2[d] = *(const v8s*)(ap + (18 + d) * 512);
    }

    #pragma unroll
    for (int p = 0; p < PB; p++) {
        int hw = grp * PB + p;
        int hy = hw / W, wx = hw % W;
        v8s bfr[9];
        #pragma unroll
        for (int d = 0; d < 9; d++) {
            int dh = d / 3, dw = d % 3;
            const uint16_t* src = sP
                + ((size_t)((n * 12 + hy + dh) * 12 + wx + dw)) * 2048
                + (t0 + l31) * 16 + lhi * 8;
            bfr[d] = *(const v8s*)src;
        }
        v16f ac0, ac1, ac2;
        #pragma unroll
        for (int e = 0; e < 16; e++) { ac0[e] = 0.f; ac1[e] = 0.f; ac2[e] = 0.f; }
        #pragma unroll
        for (int d = 0; d < 9; d++) {
            ac0 = __builtin_amdgcn_mfma_f32_32x32x16_bf16(a0[d], bfr[d], ac0, 0, 0, 0);
            ac1 = __builtin_amdgcn_mfma_f32_32x32x16_bf16(a1[d], bfr[d], ac1, 0, 0, 0);
            ac2 = __builtin_amdgcn_mfma_f32_32x32x16_bf16(a2[d], bfr[d], ac2, 0, 0, 0);
        }
        #pragma unroll
        for (int r = 0; r < 16; r++) {
            int o = (r & 3) + 8 * (r >> 2) + 4 * lhi;
            ldsF[(o * PB + p) * 130 + t0 + l31] =
                (ac0[r] + ac1[r] + ac2[r]) * scale;
        }
    }
    __syncthreads();
    if (tid < 64) {                              // scan -> LDS spike rows
        int o = tid / PB, p = tid % PB;
        float u = 0.f, v = 0.f;
        uint32_t ob[32];
        const float* xr = &ldsF[tid * 130];
        #pragma unroll
        for (int tb = 0; tb < 32; tb++) {
            float2 xa = *(const float2*)(xr + tb * 4);
            float2 xb = *(const float2*)(xr + tb * 4 + 2);
            float s0, s1, s2, s3;
            neuron_step(xa.x, u, v, s0); neuron_step(xa.y, u, v, s1);
            neuron_step(xb.x, u, v, s2); neuron_step(xb.y, u, v, s3);
            ob[tb] = (uint32_t)s0 | ((uint32_t)s1 << 8) |
                     ((uint32_t)s2 << 16) | ((uint32_t)s3 << 24);
        }
        int row = p * 32 + o;                    // c'-local
        #pragma unroll
        for (int j = 0; j < 32; j++)
            *(uint32_t*)&sbuf[row * 132 + j * 4] = ob[j];
    }
    __syncthreads();
    // phase 3: sT transpose body, c0 = grp*64; At[n][t][c'] = spike[t-1]
    {
        int t = tid >> 1, half = tid & 1;
        uint32_t wb[16];
        if (t == 0) {
            #pragma unroll
            for (int j = 0; j < 16; j++) wb[j] = 0u;
        } else {
            #pragma unroll
            for (int j = 0; j < 16; j++) {
                uint32_t lo = sbuf[(half * 32 + 2 * j) * 132 + (t - 1)] ? 0x3F80u : 0u;
                uint32_t hi = sbuf[(half * 32 + 2 * j + 1) * 132 + (t - 1)] ? 0x3F80u : 0u;
                wb[j] = lo | (hi << 16);
            }
        }
        uint16_t* dst = At + ((size_t)(n * 128 + t)) * 3200 + grp * 64 + half * 32;
        #pragma unroll
        for (int k = 0; k < 4; k++)
            *(uint4*)(dst + k * 8) =
                make_uint4(wb[k*4], wb[k*4+1], wb[k*4+2], wb[k*4+3]);
    }
}

// ---------------- FC GEMM on matrix cores (8 waves, 2x4 split) --------------
#define GLDS16(g, s) __builtin_amdgcn_global_load_lds( \
    (const __attribute__((address_space(1))) uint32_t*)(g), \
    (__attribute__((address_space(3))) uint32_t*)(s), 16, 0, 0)

__global__ __launch_bounds__(512, 4) void fc_gemm_mfma(
    const uint16_t* __restrict__ At,   // [16][128][3200] bf16 (c' order)
    const uint16_t* __restrict__ Bs,   // [3][512][3200] bf16 (c' order)
    float* __restrict__ ypart)         // [10][16][128][512] f32
{
    __shared__ uint8_t lds[65536];     // A [128][64]bf16 @0; B 3x[128][64] @16K
    int bid0 = blockIdx.x;             // 640 = 10ks x 4ob x 16n (n fastest)
    int bid = (bid0 & 7) * 80 + (bid0 >> 3);     // XCD-contiguous
    int n  = bid & 15;
    int ob = (bid >> 4) & 3;
    int ks = bid >> 6;
    int o0 = ob * 128;
    int cbase = ks * 320;

    int tid = threadIdx.x;
    int w8 = tid >> 6;                 // wave 0..7
    int wm = w8 >> 2;                  // t-half
    int wn = w8 & 3;                   // o-quarter
    int lane = tid & 63;
    int l31 = lane & 31;
    int lhi = lane >> 5;               // k-half within frag
    int rb = lane >> 3;                // staging: row-in-8
    int gsw = (lane & 7) ^ (rb & 7);   // pre-swizzled source granule

    v16f acc[2];
    #pragma unroll
    for (int mi = 0; mi < 2; mi++)
        #pragma unroll
        for (int e = 0; e < 16; e++) acc[mi][e] = 0.0f;

    const uint16_t* Abase = At + (size_t)(n * 128) * 3200 + gsw * 8;

    for (int kc = 0; kc < 5; kc++) {
        int c0 = cbase + kc * 64;
        // ---- stage A: 16 x 1KB chunks, chunk cid = i*8 + w8 ----
        #pragma unroll
        for (int i = 0; i < 2; i++) {
            int cid = i * 8 + w8;
            const uint16_t* src = Abase + (size_t)(cid * 8 + rb) * 3200 + c0;
            GLDS16(src, lds + cid * 1024);
        }
        // ---- stage B: 48 x 1KB chunks ----
        #pragma unroll
        for (int j = 0; j < 6; j++) {
            int cid = j * 8 + w8;
            int f0 = cid * 1024;
            int s = f0 >> 14;                    // split plane
            int r = ((f0 & 16383) >> 7) + rb;    // o-local row
            const uint16_t* src = Bs + (size_t)(s * 512 + o0 + r) * 3200
                                     + c0 + gsw * 8;
            GLDS16(src, lds + 16384 + f0);
        }
        __syncthreads();                         // drains vmcnt before barrier
        // ---- compute: 4 kf x (3 splits x 2 mi) MFMA per wave ----
        #pragma unroll
        for (int kf = 0; kf < 4; kf++) {
            int gc = kf * 2 + lhi;
            v8s av[2];
            #pragma unroll
            for (int mi = 0; mi < 2; mi++) {
                int t = wm * 64 + mi * 32 + l31;
                av[mi] = *(const v8s*)(lds + t * 128 + ((gc ^ (t & 7)) << 4));
            }
            #pragma unroll
            for (int s = 0; s < 3; s++) {
                int r = wn * 32 + l31;
                v8s bv = *(const v8s*)(lds + 16384 + s * 16384 + r * 128
                                       + ((gc ^ (r & 7)) << 4));
                #pragma unroll
                for (int mi = 0; mi < 2; mi++)
                    acc[mi] = __builtin_amdgcn_mfma_f32_32x32x16_bf16(
                        av[mi], bv, acc[mi], 0, 0, 0);
            }
        }
        __syncthreads();                         // LDS safe before next stage
    }
    // ---- epilogue: C/D layout col=lane&31, row=(r&3)+8*(r>>2)+4*(lane>>5) --
    float* yp = ypart + (size_t)ks * 1048576 + (size_t)n * 65536;
    int o = o0 + wn * 32 + l31;
    #pragma unroll
    for (int mi = 0; mi < 2; mi++) {
        #pragma unroll
        for (int r = 0; r < 16; r++) {
            int trow = wm * 64 + mi * 32 + (r & 3) + 8 * (r >> 2) + 4 * lhi;
            yp[trow * 512 + o] = acc[mi][r];
        }
    }
}

// ---------------- FC scan: fused 10-way reduce + LIF + delay (wide) ---------
// Block = 256 thr = 16 t x 16 o; 512 blocks = 16n x 32 o-groups.
__global__ __launch_bounds__(256) void fc_scan(
    const float* __restrict__ yp,     // [10][16][128][512]
    float* __restrict__ out)          // [16][512][128]
{
    __shared__ float ldsX[16 * 132];  // 8,448 B
    int b = blockIdx.x;               // 512
    int n = b >> 5;
    int o0 = (b & 31) * 16;
    int tid = threadIdx.x;
    int t16 = tid >> 4, ol = tid & 15;
    const float* base = yp + (size_t)n * 65536 + o0 + ol;

    #pragma unroll
    for (int tb = 0; tb < 8; tb++) {
        int t = tb * 16 + t16;
        float x = base[(size_t)t * 512];
        #pragma unroll
        for (int k = 1; k < 10; k++)
            x += base[(size_t)k * 1048576 + (size_t)t * 512];
        ldsX[ol * 132 + t] = x;
    }
    __syncthreads();
    if (tid < 16) {
        int o = o0 + tid;
        const float* xr = &ldsX[tid * 132];
        float u = 0.f, v = 0.f;
        float prev = 0.f;             // final delay_shift
        float* op = out + ((size_t)(n * 512 + o)) * T;
        for (int tb = 0; tb < 32; tb++) {
            float bv[4];
            #pragma unroll
            for (int j = 0; j < 4; j++) {
                float s;
                neuron_step(xr[tb * 4 + j], u, v, s);
                bv[j] = prev; prev = s;
            }
            *(float4*)&op[tb * 4] = make_float4(bv[0], bv[1], bv[2], bv[3]);
        }
    }
}

// ---------------- launch ----------------------------------------------------
extern "C" void kernel_launch(void* const* d_in, const int* in_sizes, int n_in,
                              void* d_out, int out_size, void* d_ws, size_t ws_size,
                              hipStream_t stream) {
    const float* spike = (const float*)d_in[0];   // [16][2][40][40][128]
    const float* c1w   = (const float*)d_in[1];   // [8][2][3][3]
    const float* c2w   = (const float*)d_in[2];   // [16][8][3][3]
    const float* c3w   = (const float*)d_in[3];   // [32][16][3][3]
    const float* p1w   = (const float*)d_in[4];   // scalar
    const float* p2w   = (const float*)d_in[5];   // scalar
    const float* fcw   = (const float*)d_in[6];   // [512][3200]
    float* out = (float*)d_out;                   // [16][512][128]

    char* ws = (char*)d_ws;
    // Lifetime-ordered map (s5 deleted; max 151,967,744):
    uint8_t*  s1    = (uint8_t*)(ws);             // -> 26,214,400
    uint16_t* Bs16  = (uint16_t*)(ws + 26214400); // -> 36,044,800 (alive->fc)
    uint16_t* Apk   = (uint16_t*)(ws + 36044800); // -> 36,100,096 (alive->conv3)
    uint16_t* s2P   = (uint16_t*)(ws + 36100096); // -> 67,819,520
    uint8_t*  s3    = (uint8_t*)(ws + 67819520);  // -> 80,926,720
    uint16_t* s4P   = (uint16_t*)(ws + 80926720); // -> 90,363,904
    uint16_t* At16  = (uint16_t*)(ws + 96917504); // -> 110,024,704
    float*    ypart = (float*)(ws + 110024704);   // -> 151,967,744

    conv1_prep<<<6862, 256, 0, stream>>>(spike, c1w, s1,
                                         fcw, c2w, c3w, Bs16, Apk, s2P, s4P);

    pool_pad<8, 8, 20, 20><<<800, 64, 0, stream>>>(s1, p1w, s2P);
    conv_scan_mfma<16, 4, 20, 20><<<1600, 256, 0, stream>>>(s2P, Apk, 100.0f, s3);

    pool_pad<16, 4, 10, 10><<<400, 64, 0, stream>>>(s3, p2w, s4P);
    conv3_scan_at<<<800, 256, 0, stream>>>(s4P, Apk + 13824, 100.0f, At16);

    fc_gemm_mfma<<<640, 512, 0, stream>>>(At16, Bs16, ypart);
    fc_scan<<<512, 256, 0, stream>>>(ypart, out);
}